// Round 9
// baseline (246.129 us; speedup 1.0000x reference)
//
#include <hip/hip_runtime.h>
#include <hip/hip_bf16.h>

typedef unsigned short ushort;
typedef __attribute__((ext_vector_type(8))) short short8;
typedef __attribute__((ext_vector_type(4))) float f32x4;

constexpr int N_  = 4096;
constexpr int TD_ = 768;
constexpr int ID_ = 512;
constexpr int H_  = 256;
constexpr int HD_ = 64;
constexpr int E_  = 131072;
constexpr int SPLITS = 8;  // R18: halves Op/lp traffic at same steady-state occupancy
constexpr float QSCALE = 0.125f * 1.44269504088896f;  // 1/sqrt(64) * log2(e)

#define MFMA16(a, b, c) __builtin_amdgcn_mfma_f32_16x16x32_bf16(a, b, c, 0, 0, 0)

__device__ inline ushort f2bf(float x) {
    union { float f; unsigned u; } v; v.f = x;
    unsigned r = v.u + 0x7fff + ((v.u >> 16) & 1);
    return (ushort)(r >> 16);
}
__device__ inline float lo2f(unsigned u) { union { unsigned x; float f; } v; v.x = u << 16; return v.f; }
__device__ inline float hi2f(unsigned u) { union { unsigned x; float f; } v; v.x = u & 0xffff0000u; return v.f; }

__device__ inline float exp2r(float x) {
    float r;
    asm("v_exp_f32 %0, %1" : "=v"(r) : "v"(x));
    return r;
}
__device__ inline unsigned pkbf(float lo, float hi) {
    union { float f; unsigned u; } a, b; a.f = lo; b.f = hi;
    return __builtin_amdgcn_perm(b.u + 0x8000u, a.u + 0x8000u, 0x07060302u);
}

__device__ inline void gl_lds16(const void* g, void* l) {
    __builtin_amdgcn_global_load_lds((const __attribute__((address_space(1))) unsigned int*)g,
                                     (__attribute__((address_space(3))) unsigned int*)l, 16, 0, 0);
}

// Stage 64x64 bf16 tile into LDS (wave-uniform base + lane*16B), XOR-swizzled 16B chunks.
__device__ inline void stage64(const ushort* g, long long strideEl, ushort* lds, int w, int l) {
    int r8 = l >> 3;
    int cc = (l & 7) ^ r8;
    #pragma unroll
    for (int p = 0; p < 2; p++) {
        int row = w * 16 + p * 8 + r8;
        gl_lds16(g + (long long)row * strideEl + cc * 8, lds + (w * 16 + p * 8) * 64);
    }
}
// Stage 16x64 bf16 tile (B for 64x16 GEMM tiles): waves 0,1 cover 8 rows each. [verified R8/R9]
__device__ inline void stageB16(const ushort* g, long long strideEl, ushort* lds, int w, int l) {
    if (w < 2) {
        int r8 = l >> 3;
        int row = w * 8 + r8;
        int cc = (l & 7) ^ (row & 7);
        gl_lds16(g + (long long)row * strideEl + cc * 8, lds + w * 512);
    }
}
__device__ inline int swz(int row, int kOff) {
    return row * 64 + ((((kOff >> 3) ^ (row & 7))) << 3);
}

// ---------------- prep: cvt (0..2591) | transposes (2592..2751) | edge count (2752..3263) ----------------

__global__ __launch_bounds__(256) void k_prep(const float* __restrict__ text, const float* __restrict__ img,
                                              const float* __restrict__ tw, const float* __restrict__ iw,
                                              const float* __restrict__ wq, const float* __restrict__ wk,
                                              const float* __restrict__ wv, const float* __restrict__ wo,
                                              const float* __restrict__ g1w, const float* __restrict__ g2w,
                                              const int* __restrict__ edst, int* __restrict__ indeg,
                                              ushort* __restrict__ textbf, ushort* __restrict__ imgbf,
                                              ushort* __restrict__ wobf,
                                              ushort* __restrict__ twT, ushort* __restrict__ iwT,
                                              ushort* __restrict__ wqT, ushort* __restrict__ wkT,
                                              ushort* __restrict__ wvT, ushort* __restrict__ g1wT,
                                              ushort* __restrict__ g2wT) {
    __shared__ float Ts[64][65];
    const int b = blockIdx.x;
    const int t = threadIdx.x;
    if (b >= 2752) {  // edge count
        int e = (b - 2752) * 256 + t;
        atomicAdd(&indeg[edst[e]], 1);
        return;
    }
    if (b < 2592) {  // linear bf16 cvt: text | img | wo
        size_t base = ((size_t)b * 256 + t) * 8;
        const size_t TXE = (size_t)N_ * TD_, IME = (size_t)N_ * ID_;
        const float* src; ushort* dst;
        if (base < TXE) { src = text + base; dst = textbf + base; }
        else if (base < TXE + IME) { src = img + (base - TXE); dst = imgbf + (base - TXE); }
        else { src = wo + (base - TXE - IME); dst = wobf + (base - TXE - IME); }
        float4 x = *(const float4*)src;
        float4 y = *(const float4*)(src + 4);
        ushort o[8] = { f2bf(x.x), f2bf(x.y), f2bf(x.z), f2bf(x.w),
                        f2bf(y.x), f2bf(y.y), f2bf(y.z), f2bf(y.w) };
        *(short8*)dst = *(const short8*)o;
        return;
    }
    int wb = b - 2592;
    const float* src; ushort* dst; int R, tile;
    if (wb < 48)       { src = tw;  dst = twT;  R = 768; tile = wb; }
    else if (wb < 80)  { src = iw;  dst = iwT;  R = 512; tile = wb - 48; }
    else if (wb < 96)  { src = wq;  dst = wqT;  R = 256; tile = wb - 80; }
    else if (wb < 112) { src = wk;  dst = wkT;  R = 256; tile = wb - 96; }
    else if (wb < 128) { src = wv;  dst = wvT;  R = 256; tile = wb - 112; }
    else if (wb < 144) { src = g1w; dst = g1wT; R = 256; tile = wb - 128; }
    else               { src = g2w; dst = g2wT; R = 256; tile = wb - 144; }
    const int r0 = (tile >> 2) * 64, c0 = (tile & 3) * 64;
    #pragma unroll
    for (int u = 0; u < 16; u++) {
        int lin = t + u * 256;
        int r = lin >> 6, c = lin & 63;
        Ts[r][c] = src[(size_t)(r0 + r) * 256 + c0 + c];
    }
    __syncthreads();
    #pragma unroll
    for (int u = 0; u < 16; u++) {
        int lin = t + u * 256;
        int c = lin >> 6, r = lin & 63;
        dst[(size_t)(c0 + c) * R + r0 + r] = f2bf(Ts[r][c]);
    }
}

// ---------------- combined projection 64x16 tiles (blocks 0..1023, XCD-clustered) + degree scan ----------------

__global__ __launch_bounds__(256, 4) void k_combined16(const ushort* __restrict__ text, const ushort* __restrict__ img,
                                                       const ushort* __restrict__ twT, const ushort* __restrict__ iwT,
                                                       const float* __restrict__ tb, const float* __restrict__ ib,
                                                       const int* __restrict__ indeg, int* __restrict__ offs,
                                                       float* __restrict__ dinv, ushort* __restrict__ out) {
    __shared__ ushort As[2][4096];
    __shared__ ushort Bs[2][1024];
    __shared__ ushort Cs[64 * 24];
    __shared__ int sums[256];
    const int b = blockIdx.x;
    const int t = threadIdx.x;
    if (b == 1024) {  // exclusive scan of indeg + dinv [verified R8]
        int v[16]; int ssum = 0; int base = t * 16;
        #pragma unroll
        for (int k2 = 0; k2 < 16; k2++) { v[k2] = indeg[base + k2]; ssum += v[k2]; }
        sums[t] = ssum;
        __syncthreads();
        for (int off = 1; off < 256; off <<= 1) {
            int x = (t >= off) ? sums[t - off] : 0;
            __syncthreads();
            sums[t] += x;
            __syncthreads();
        }
        int excl = sums[t] - ssum;
        #pragma unroll
        for (int k2 = 0; k2 < 16; k2++) {
            offs[base + k2] = excl;
            excl += v[k2];
            dinv[base + k2] = 1.f / sqrtf((float)(v[k2] + 1));
        }
        return;
    }
    const int xcd = b & 7, slot = b >> 3;
    const int bm = (xcd * 8 + (slot >> 4)) * 64, bn = (slot & 15) * 16;
    const int w = t >> 6, l = t & 63, q = l >> 4, i = l & 15;
    f32x4 acc1 = {0, 0, 0, 0}, acc2 = {0, 0, 0, 0};
    auto stC = [&](int c, int buf) {
        if (c < 12) {
            stage64(text + (size_t)bm * TD_ + c * 64, TD_, As[buf], w, l);
            stageB16(twT + (size_t)bn * TD_ + c * 64, TD_, Bs[buf], w, l);
        } else {
            stage64(img + (size_t)bm * ID_ + (c - 12) * 64, ID_, As[buf], w, l);
            stageB16(iwT + (size_t)bn * ID_ + (c - 12) * 64, ID_, Bs[buf], w, l);
        }
    };
    stC(0, 0);
    for (int c = 0; c < 20; c++) {
        __syncthreads();
        if (c + 1 < 20) stC(c + 1, (c + 1) & 1);
        const ushort* Ab = As[c & 1];
        const ushort* Bb = Bs[c & 1];
        #pragma unroll
        for (int kb = 0; kb < 2; kb++) {
            short8 af = *(const short8*)&Ab[swz(w * 16 + i, kb * 32 + q * 8)];
            short8 bfr = *(const short8*)&Bb[swz(i, kb * 32 + q * 8)];
            if (c < 12) acc1 = MFMA16(af, bfr, acc1);
            else        acc2 = MFMA16(af, bfr, acc2);
        }
    }
    __syncthreads();
    float b1 = tb[bn + i], b2 = ib[bn + i];
    #pragma unroll
    for (int r = 0; r < 4; r++) {
        float v = fmaxf(acc1[r] + b1, 0.f) + fmaxf(acc2[r] + b2, 0.f);
        Cs[(w * 16 + q * 4 + r) * 24 + i] = f2bf(v);
    }
    __syncthreads();
    if (t < 128) {
        int row = t >> 1, h8 = (t & 1) * 8;
        *(short8*)(out + (size_t)(bm + row) * H_ + bn + h8) = *(const short8*)&Cs[row * 24 + h8];
    }
}

// ---------------- QKV (0..767, XCD-clustered) + scatter (768..1279) + wo-fold (1280..1295)
//                  + bp (1296) + W3 = g2w@cls (1297..1300) + cvec (1301)  [R19] ----------------

__global__ __launch_bounds__(256) void k_qkv_scatfold(const ushort* __restrict__ A,
                                                      const ushort* __restrict__ WqT, const ushort* __restrict__ WkT,
                                                      const ushort* __restrict__ WvT,
                                                      const float* __restrict__ bq, const float* __restrict__ bk,
                                                      const float* __restrict__ bv,
                                                      ushort* __restrict__ Qg, ushort* __restrict__ Kg,
                                                      ushort* __restrict__ Vtg,
                                                      const int* __restrict__ esrc, const int* __restrict__ edst,
                                                      const int* __restrict__ offs, const float* __restrict__ dinv,
                                                      int* __restrict__ pos, int* __restrict__ ssrc,
                                                      float* __restrict__ swv,
                                                      const ushort* __restrict__ g1wT, const ushort* __restrict__ wobf,
                                                      const float* __restrict__ bo,
                                                      ushort* __restrict__ WpT, float* __restrict__ bp,
                                                      const float* __restrict__ g2wf, const float* __restrict__ cwf,
                                                      const float* __restrict__ g2bf, const float* __restrict__ cbf,
                                                      float* __restrict__ W3, float* __restrict__ cvec) {
    __shared__ ushort As[2][4096];
    __shared__ ushort Bs[2][4096];
    __shared__ ushort Cs[64 * 72];
    const int b = blockIdx.x;
    const int t = threadIdx.x;
    const int w = t >> 6, l = t & 63, q = l >> 4, i = l & 15;

    if (b >= 768) {
        if (b < 1280) {  // edge scatter
            int e = (b - 768) * 256 + t;
            int s = esrc[e], d = edst[e];
            int p = atomicAdd(&pos[d], 1);
            int idx = offs[d] + p;
            ssrc[idx] = s;
            swv[idx] = dinv[s] * dinv[d];
            return;
        }
        if (b >= 1297) {  // R19: W3[r][c] = sum_k g2w[r][k]*cls[k][c]; cvec[c] = cls^T g2b + cb
            if (b == 1301) {
                if (t < 3) {
                    float acc = 0.f;
                    for (int d = 0; d < 256; d++) acc += cwf[d * 3 + t] * g2bf[d];
                    cvec[t] = acc + cbf[t];
                }
                return;
            }
            int r = (b - 1297) * 64 + (t & 63), c = t >> 6;
            if (c < 3) {
                float acc = 0.f;
                const float* row = g2wf + (size_t)r * 256;
                for (int k = 0; k < 256; k++) acc += row[k] * cwf[k * 3 + c];
                W3[r * 3 + c] = acc;
            }
            return;
        }
        if (b == 1296) {  // bp[c] = sum_m bo[m] * g1wT[c][m]
            float acc = 0.f;
            const ushort* row = g1wT + (size_t)t * 256;
            for (int m8 = 0; m8 < 256; m8 += 8) {
                #pragma unroll
                for (int j = 0; j < 8; j++) acc += bo[m8 + j] * lo2f(((unsigned)row[m8 + j]) << 16);
            }
            bp[t] = acc;
            return;
        }
        // wo-fold tile: WpT[a][b2] = sum_m g1wT[a][m]*wobf[b2][m]
        const int f = b - 1280;
        const int bm = (f >> 2) * 64, bn = (f & 3) * 64;
        f32x4 acc[4];
        #pragma unroll
        for (int nt = 0; nt < 4; nt++) acc[nt] = (f32x4){0, 0, 0, 0};
        stage64(g1wT + (size_t)bm * H_, H_, As[0], w, l);
        stage64(wobf + (size_t)bn * H_, H_, Bs[0], w, l);
        for (int c = 0; c < 4; c++) {
            __syncthreads();
            if (c < 3) {
                stage64(g1wT + (size_t)bm * H_ + (c + 1) * 64, H_, As[(c + 1) & 1], w, l);
                stage64(wobf + (size_t)bn * H_ + (c + 1) * 64, H_, Bs[(c + 1) & 1], w, l);
            }
            const ushort* Ab = As[c & 1];
            const ushort* Bb = Bs[c & 1];
            #pragma unroll
            for (int kb = 0; kb < 2; kb++) {
                short8 af = *(const short8*)&Ab[swz(w * 16 + i, kb * 32 + q * 8)];
                #pragma unroll
                for (int nt = 0; nt < 4; nt++) {
                    short8 bfr = *(const short8*)&Bb[swz(nt * 16 + i, kb * 32 + q * 8)];
                    acc[nt] = MFMA16(af, bfr, acc[nt]);
                }
            }
        }
        __syncthreads();
        #pragma unroll
        for (int nt = 0; nt < 4; nt++)
            #pragma unroll
            for (int r = 0; r < 4; r++)
                Cs[(w * 16 + q * 4 + r) * 72 + nt * 16 + i] = f2bf(acc[nt][r]);
        __syncthreads();
        int rr = t >> 2, c16 = (t & 3) * 16;
        short8 v0 = *(const short8*)&Cs[rr * 72 + c16];
        short8 v1 = *(const short8*)&Cs[rr * 72 + c16 + 8];
        ushort* dstp = WpT + (size_t)(bm + rr) * H_ + bn + c16;
        *(short8*)dstp = v0;
        *(short8*)(dstp + 8) = v1;
        return;
    }

    // QKV: z = b>>8; within z, XCD-clustered remap [R18]
    const int z = b >> 8, r = b & 255;
    const int xcd = r & 7, slot = r >> 3;
    const int bm = (xcd * 8 + (slot >> 2)) * 64, head = slot & 3;
    const ushort* WT = (z == 0) ? WqT : (z == 1) ? WkT : WvT;
    const float* bias = (z == 0) ? bq : (z == 1) ? bk : bv;
    f32x4 acc[4];
    #pragma unroll
    for (int nt = 0; nt < 4; nt++) acc[nt] = (f32x4){0, 0, 0, 0};

    stage64(A + (size_t)bm * H_, H_, As[0], w, l);
    stage64(WT + (size_t)(head * 64) * H_, H_, Bs[0], w, l);
    for (int c = 0; c < 4; c++) {
        __syncthreads();
        if (c < 3) {
            stage64(A + (size_t)bm * H_ + (c + 1) * 64, H_, As[(c + 1) & 1], w, l);
            stage64(WT + (size_t)(head * 64) * H_ + (c + 1) * 64, H_, Bs[(c + 1) & 1], w, l);
        }
        const ushort* Ab = As[c & 1];
        const ushort* Bb = Bs[c & 1];
        #pragma unroll
        for (int kb = 0; kb < 2; kb++) {
            short8 af = *(const short8*)&Ab[swz(w * 16 + i, kb * 32 + q * 8)];
            #pragma unroll
            for (int nt = 0; nt < 4; nt++) {
                short8 bfr = *(const short8*)&Bb[swz(nt * 16 + i, kb * 32 + q * 8)];
                acc[nt] = MFMA16(af, bfr, acc[nt]);
            }
        }
    }
    __syncthreads();
    #pragma unroll
    for (int nt = 0; nt < 4; nt++) {
        float bv_ = bias[head * 64 + nt * 16 + i];
        #pragma unroll
        for (int r2 = 0; r2 < 4; r2++) {
            float v = acc[nt][r2] + bv_;
            if (z == 0) v *= QSCALE;
            if (z < 2) Cs[(w * 16 + q * 4 + r2) * 72 + nt * 16 + i] = f2bf(v);
            else       Cs[(nt * 16 + i) * 72 + w * 16 + q * 4 + r2] = f2bf(v);  // transposed [d][n]
        }
    }
    __syncthreads();
    int rr = t >> 2, c16 = (t & 3) * 16;
    short8 v0 = *(const short8*)&Cs[rr * 72 + c16];
    short8 v1 = *(const short8*)&Cs[rr * 72 + c16 + 8];
    ushort* dst;
    if (z < 2) dst = ((z == 0) ? Qg : Kg) + (size_t)head * N_ * HD_ + (size_t)(bm + rr) * HD_ + c16;
    else       dst = Vtg + (size_t)head * HD_ * N_ + (size_t)rr * N_ + bm + c16;
    *(short8*)dst = v0;
    *(short8*)(dst + 8) = v1;
}

// ---------------- flash attention: S^T math, NO K/V staging (direct L1/L2 reads), barrier-free ----------------
// R21: K/V fragments read straight from global (guide Common-mistake #7: K/V are L2-resident,
// 512 KB/head; all 4 waves read IDENTICAL kf/vf addresses -> L1 broadcast). Removes all gl_lds
// staging and BOTH per-tile barriers; only Ps (wave-private) remains in LDS (18.4 KB).
// Byte-identical math to R16/R18 (same fragments, different data path).

__global__ __launch_bounds__(256) void k_attn_mfma(const ushort* __restrict__ Qg, const ushort* __restrict__ Kg,
                                                   const ushort* __restrict__ Vtg, ushort* __restrict__ Op,
                                                   float* __restrict__ lp) {
    __shared__ ushort Ps[4][2][16 * 72];
    const int head = blockIdx.y, r0 = blockIdx.x * 128, z = blockIdx.z;
    const int t = threadIdx.x, w = t >> 6, l = t & 63, q = l >> 4, i = l & 15;
    const int rw = (i ^ (i >> 1)) & 7;
    ushort* Pw0 = &Ps[w][0][0];
    ushort* Pw1 = &Ps[w][1][0];

    short8 qf[2][2];  // [qt][kb]
    #pragma unroll
    for (int qt = 0; qt < 2; qt++)
        #pragma unroll
        for (int kb = 0; kb < 2; kb++)
            qf[qt][kb] = *(const short8*)(Qg + ((size_t)head * N_ + r0 + qt * 64 + w * 16 + i) * HD_ + kb * 32 + q * 8);

    f32x4 Oacc[2][4];
    float lacc[2] = {0.f, 0.f};
    #pragma unroll
    for (int qt = 0; qt < 2; qt++)
        #pragma unroll
        for (int dt = 0; dt < 4; dt++) Oacc[qt][dt] = (f32x4){0, 0, 0, 0};

    const int NT = 64 / SPLITS;
    const int cb0 = z * NT;
    const ushort* Kb = Kg + (size_t)head * N_ * HD_;   // [n][d]
    const ushort* Vb = Vtg + (size_t)head * HD_ * N_;  // [d][n]

    for (int it = 0; it < NT; it++) {
        const int n0 = (cb0 + it) * 64;

        // S^T for both query tiles; kf direct from global (contiguous 16B along d)
        f32x4 St[2][4];
        #pragma unroll
        for (int qt = 0; qt < 2; qt++)
            #pragma unroll
            for (int kt = 0; kt < 4; kt++) St[qt][kt] = (f32x4){0, 0, 0, 0};
        #pragma unroll
        for (int kb = 0; kb < 2; kb++) {
            #pragma unroll
            for (int kt = 0; kt < 4; kt++) {
                short8 kf = *(const short8*)&Kb[(size_t)(n0 + kt * 16 + i) * HD_ + kb * 32 + q * 8];
                St[0][kt] = MFMA16(kf, qf[0][kb], St[0][kt]);
                St[1][kt] = MFMA16(kf, qf[1][kb], St[1][kt]);
            }
        }
        // exp/pack BOTH query tiles into their own Ps halves (wave-private, no barrier needed)
        #pragma unroll
        for (int kt = 0; kt < 4; kt++) {
            float a0 = exp2r(St[0][kt][0]), a1 = exp2r(St[0][kt][1]);
            float a2 = exp2r(St[0][kt][2]), a3 = exp2r(St[0][kt][3]);
            lacc[0] += (a0 + a1) + (a2 + a3);
            float b0 = exp2r(St[1][kt][0]), b1 = exp2r(St[1][kt][1]);
            float b2 = exp2r(St[1][kt][2]), b3 = exp2r(St[1][kt][3]);
            lacc[1] += (b0 + b1) + (b2 + b3);
            int off = i * 72 + (((2 * kt + (q >> 1)) ^ rw) << 3) + ((q & 1) << 2);
            uint2 va; va.x = pkbf(a0, a1); va.y = pkbf(a2, a3);
            *(uint2*)&Pw0[off] = va;
            uint2 vb; vb.x = pkbf(b0, b1); vb.y = pkbf(b2, b3);
            *(uint2*)&Pw1[off] = vb;
        }
        // fused PV: vf direct from global (contiguous 16B along n), used for both query tiles
        #pragma unroll
        for (int kb = 0; kb < 2; kb++) {
            int poff = i * 72 + (((4 * kb + q) ^ rw) << 3);
            short8 pf0 = *(const short8*)&Pw0[poff];
            short8 pf1 = *(const short8*)&Pw1[poff];
            #pragma unroll
            for (int dt = 0; dt < 4; dt++) {
                short8 vf = *(const short8*)&Vb[(size_t)(dt * 16 + i) * N_ + n0 + kb * 32 + q * 8];
                Oacc[0][dt] = MFMA16(vf, pf0, Oacc[0][dt]);
                Oacc[1][dt] = MFMA16(vf, pf1, Oacc[1][dt]);
            }
        }
    }

    #pragma unroll
    for (int qt = 0; qt < 2; qt++) {
        lacc[qt] += __shfl_xor(lacc[qt], 16);
        lacc[qt] += __shfl_xor(lacc[qt], 32);
    }

    const size_t sh = ((size_t)z * 4 + head) * N_;
    #pragma unroll
    for (int qt = 0; qt < 2; qt++) {
        const int row = r0 + qt * 64 + w * 16 + i;
        #pragma unroll
        for (int dt = 0; dt < 4; dt++) {
            uint2 v;
            v.x = pkbf(Oacc[qt][dt][0], Oacc[qt][dt][1]);
            v.y = pkbf(Oacc[qt][dt][2], Oacc[qt][dt][3]);
            *(uint2*)&Op[(sh + row) * HD_ + dt * 16 + q * 4] = v;
        }
        if (l < 16) lp[sh + r0 + qt * 64 + w * 16 + l] = lacc[qt];
    }
}

// merge SPLITS splits -> obuf bf16 [N][H]
__global__ __launch_bounds__(256) void k_attn_merge(const ushort* __restrict__ Op, const float* __restrict__ lp,
                                                    ushort* __restrict__ obuf) {
    const int t = threadIdx.x;
    const int idx = blockIdx.x * 16 + (t >> 4);
    const int h = idx >> 12, n = idx & 4095;
    const int d4 = (t & 15) * 4;
    float lsum = 0.f;
    float acc[4] = {0.f, 0.f, 0.f, 0.f};
    #pragma unroll
    for (int s = 0; s < SPLITS; s++) {
        size_t sh = ((size_t)s * 4 + h) * N_ + n;
        lsum += lp[sh];
        uint2 o4 = *(const uint2*)&Op[sh * HD_ + d4];
        acc[0] += lo2f(o4.x); acc[1] += hi2f(o4.x);
        acc[2] += lo2f(o4.y); acc[3] += hi2f(o4.y);
    }
    float inv = 1.f / lsum;
    uint2 res;
    res.x = pkbf(acc[0] * inv, acc[1] * inv);
    res.y = pkbf(acc[2] * inv, acc[3] * inv);
    *(uint2*)&obuf[(size_t)n * H_ + h * HD_ + d4] = res;
}

// ---------------- bf16 MFMA GEMM, 64x16 tiles (grid 64x16) [verified R9] ----------------

template <bool BIAS>
__global__ __launch_bounds__(256, 4) void k_gemm16(const ushort* __restrict__ A, const ushort* __restrict__ BT,
                                                   const float* __restrict__ bias, ushort* __restrict__ outb) {
    __shared__ ushort As[2][4096];
    __shared__ ushort Bs[2][1024];
    __shared__ ushort Cs[64 * 24];
    const int bm = blockIdx.x * 64, bn = blockIdx.y * 16;
    const int t = threadIdx.x, w = t >> 6, l = t & 63, q = l >> 4, i = l & 15;
    f32x4 acc = {0, 0, 0, 0};
    stage64(A + (size_t)bm * H_, H_, As[0], w, l);
    stageB16(BT + (size_t)bn * H_, H_, Bs[0], w, l);
    for (int c = 0; c < 4; c++) {
        __syncthreads();
        if (c < 3) {
            stage64(A + (size_t)bm * H_ + (c + 1) * 64, H_, As[(c + 1) & 1], w, l);
            stageB16(BT + (size_t)bn * H_ + (c + 1) * 64, H_, Bs[(c + 1) & 1], w, l);
        }
        const ushort* Ab = As[c & 1];
        const ushort* Bb = Bs[c & 1];
        #pragma unroll
        for (int kb = 0; kb < 2; kb++) {
            short8 af = *(const short8*)&Ab[swz(w * 16 + i, kb * 32 + q * 8)];
            short8 bfr = *(const short8*)&Bb[swz(i, kb * 32 + q * 8)];
            acc = MFMA16(af, bfr, acc);
        }
    }
    __syncthreads();
    float bb = BIAS ? bias[bn + i] : 0.f;
    #pragma unroll
    for (int r = 0; r < 4; r++)
        Cs[(w * 16 + q * 4 + r) * 24 + i] = f2bf(acc[r] + bb);
    __syncthreads();
    if (t < 128) {
        int row = t >> 1, h8 = (t & 1) * 8;
        *(short8*)(outb + (size_t)(bm + row) * H_ + bn + h8) = *(const short8*)&Cs[row * 24 + h8];
    }
}

// ---------------- R20: GCN layer-1 aggregation FUSED with t3 = relu(agg+bias) @ W3 ----------------

__global__ __launch_bounds__(256) void k_agg1t3(const ushort* __restrict__ h, const int* __restrict__ ssrc,
                                                const float* __restrict__ sw, const int* __restrict__ offs,
                                                const int* __restrict__ indeg, const float* __restrict__ dinv,
                                                const float* __restrict__ bias, const float* __restrict__ W3,
                                                float* __restrict__ t3) {
    const int t = threadIdx.x;
    const int j = __builtin_amdgcn_readfirstlane(blockIdx.x * 4 + (t >> 6));
    const int l = t & 63;
    const int d0 = l * 4;
    float dj = dinv[j];
    uint2 hv = *(const uint2*)&h[(size_t)j * H_ + d0];
    float s2 = dj * dj;
    float a0 = s2 * lo2f(hv.x), a1 = s2 * hi2f(hv.x), a2 = s2 * lo2f(hv.y), a3 = s2 * hi2f(hv.y);
    int start = offs[j], cnt = indeg[j];
    for (int e = 0; e < cnt; e++) {
        int s = ssrc[start + e];
        float wg = sw[start + e];
        uint2 v = *(const uint2*)&h[(size_t)s * H_ + d0];
        a0 += wg * lo2f(v.x); a1 += wg * hi2f(v.x);
        a2 += wg * lo2f(v.y); a3 += wg * hi2f(v.y);
    }
    a0 = fmaxf(a0 + bias[d0], 0.f);
    a1 = fmaxf(a1 + bias[d0 + 1], 0.f);
    a2 = fmaxf(a2 + bias[d0 + 2], 0.f);
    a3 = fmaxf(a3 + bias[d0 + 3], 0.f);
    // t3 contribution of channels d0..d0+3 (W3 rows d0..d0+3, 12 consecutive f32)
    const float* wr = W3 + d0 * 3;
    float4 wa = *(const float4*)(wr);
    float4 wb = *(const float4*)(wr + 4);
    float4 wc = *(const float4*)(wr + 8);
    float p0 = a0 * wa.x + a1 * wa.w + a2 * wb.z + a3 * wc.y;
    float p1 = a0 * wa.y + a1 * wb.x + a2 * wb.w + a3 * wc.z;
    float p2 = a0 * wa.z + a1 * wb.y + a2 * wc.x + a3 * wc.w;
    #pragma unroll
    for (int off = 32; off > 0; off >>= 1) {
        p0 += __shfl_xor(p0, off);
        p1 += __shfl_xor(p1, off);
        p2 += __shfl_xor(p2, off);
    }
    if (l == 0) {
        t3[j * 3 + 0] = p0;
        t3[j * 3 + 1] = p1;
        t3[j * 3 + 2] = p2;
    }
}

// ---------------- R19: 3-dim aggregation + const -> out. Lanes over edges (handles deg>64). ----------------

__global__ __launch_bounds__(256) void k_agg3(const float* __restrict__ t3, const int* __restrict__ ssrc,
                                              const float* __restrict__ sw, const int* __restrict__ offs,
                                              const int* __restrict__ indeg, const float* __restrict__ dinv,
                                              const float* __restrict__ cvec, float* __restrict__ out) {
    const int t = threadIdx.x;
    const int j = __builtin_amdgcn_readfirstlane(blockIdx.x * 4 + (t >> 6));
    const int l = t & 63;
    int start = offs[j], cnt = indeg[j];
    float p0 = 0.f, p1 = 0.f, p2 = 0.f;
    for (int e = l; e < cnt; e += 64) {
        int s = ssrc[start + e];
        float wg = sw[start + e];
        p0 += wg * t3[s * 3 + 0];
        p1 += wg * t3[s * 3 + 1];
        p2 += wg * t3[s * 3 + 2];
    }
    #pragma unroll
    for (int off = 32; off > 0; off >>= 1) {
        p0 += __shfl_xor(p0, off);
        p1 += __shfl_xor(p1, off);
        p2 += __shfl_xor(p2, off);
    }
    if (l == 0) {
        float dj = dinv[j];
        float s2 = dj * dj;
        out[j * 3 + 0] = p0 + s2 * t3[j * 3 + 0] + cvec[0];
        out[j * 3 + 1] = p1 + s2 * t3[j * 3 + 1] + cvec[1];
        out[j * 3 + 2] = p2 + s2 * t3[j * 3 + 2] + cvec[2];
    }
}

// ---------------- launch ----------------

extern "C" void kernel_launch(void* const* d_in, const int* in_sizes, int n_in,
                              void* d_out, int out_size, void* d_ws, size_t ws_size,
                              hipStream_t stream) {
    const float* text = (const float*)d_in[0];
    const float* img  = (const float*)d_in[1];
    const int*   eidx = (const int*)d_in[2];
    const float* tw  = (const float*)d_in[3];
    const float* tb  = (const float*)d_in[4];
    const float* iw  = (const float*)d_in[5];
    const float* ib  = (const float*)d_in[6];
    const float* wq  = (const float*)d_in[7];
    const float* bq  = (const float*)d_in[8];
    const float* wk  = (const float*)d_in[9];
    const float* bk  = (const float*)d_in[10];
    const float* wv  = (const float*)d_in[11];
    const float* bv  = (const float*)d_in[12];
    const float* wo  = (const float*)d_in[13];
    const float* bo  = (const float*)d_in[14];
    const float* g1w = (const float*)d_in[15];
    const float* g1b = (const float*)d_in[16];
    const float* g2w = (const float*)d_in[17];
    const float* g2b = (const float*)d_in[18];
    const float* cw  = (const float*)d_in[19];
    const float* cbv = (const float*)d_in[20];

    char* W = (char*)d_ws;
    size_t cur = 0;
    auto alloc = [&](size_t sz) { char* p = W + cur; cur += (sz + 255) & ~(size_t)255; return p; };

    // persistent region
    float* dinv  = (float*)alloc(N_ * 4);
    float* swv   = (float*)alloc(E_ * 4);
    int* indeg   = (int*)alloc(N_ * 4);   // indeg, offs, pos contiguous (each 16 KB, 256-aligned)
    int* offs    = (int*)alloc(N_ * 4);
    int* pos     = (int*)alloc(N_ * 4);
    int* ssrc    = (int*)alloc(E_ * 4);
    ushort* Qg   = (ushort*)alloc((size_t)N_ * H_ * 2);
    ushort* Kg   = (ushort*)alloc((size_t)N_ * H_ * 2);
    ushort* Vtg  = (ushort*)alloc((size_t)N_ * H_ * 2);
    ushort* obuf = (ushort*)alloc((size_t)N_ * H_ * 2);
    ushort* WpT  = (ushort*)alloc((size_t)H_ * H_ * 2);
    float* bp    = (float*)alloc(H_ * 4);
    ushort* g1wT = (ushort*)alloc((size_t)H_ * H_ * 2);
    ushort* g2wT = (ushort*)alloc((size_t)H_ * H_ * 2);
    ushort* wobf = (ushort*)alloc((size_t)H_ * H_ * 2);
    float* lp    = (float*)alloc((size_t)SPLITS * 4 * N_ * 4);
    float* t3    = (float*)alloc((size_t)N_ * 3 * 4);
    float* W3    = (float*)alloc(256 * 3 * 4);
    float* cvec  = (float*)alloc(16);
    char* S = W + cur;  // phase-overlaid scratch

    // phase 1: conversions + projections (~13 MB)
    ushort* textbf = (ushort*)S;
    ushort* imgbf  = textbf + (size_t)N_ * TD_;
    ushort* twT    = imgbf + (size_t)N_ * ID_;
    ushort* iwT    = twT + (size_t)TD_ * H_;
    ushort* wqT    = iwT + (size_t)ID_ * H_;
    ushort* wkT    = wqT + (size_t)H_ * H_;
    ushort* wvT    = wkT + (size_t)H_ * H_;
    ushort* combbf = wvT + (size_t)H_ * H_;
    // phase 2: Op = SPLITS*4*N*64 bf16 = 16 MB (overlays phase 1)
    ushort* Op = (ushort*)S;
    // phase 3: post-attention (Op dead after merge)
    ushort* hbuf  = (ushort*)S;

    const int* esrc = eidx;
    const int* edst = eidx + E_;

    // R20: k_init dispatch replaced by one memset node (indeg+offs+pos are contiguous)
    hipMemsetAsync(indeg, 0, (size_t)3 * N_ * 4, stream);
    k_prep<<<dim3(3264), dim3(256), 0, stream>>>(text, img, tw, iw, wq, wk, wv, wo, g1w, g2w,
                                                 edst, indeg,
                                                 textbf, imgbf, wobf, twT, iwT, wqT, wkT, wvT, g1wT, g2wT);
    k_combined16<<<dim3(1025), dim3(256), 0, stream>>>(textbf, imgbf, twT, iwT, tb, ib,
                                                       indeg, offs, dinv, combbf);
    k_qkv_scatfold<<<dim3(1302), dim3(256), 0, stream>>>(combbf, wqT, wkT, wvT, bq, bk, bv, Qg, Kg, Vtg,
                                                         esrc, edst, offs, dinv, pos, ssrc, swv,
                                                         g1wT, wobf, bo, WpT, bp,
                                                         g2w, cw, g2b, cbv, W3, cvec);
    k_attn_mfma<<<dim3(32, 4, SPLITS), dim3(256), 0, stream>>>(Qg, Kg, Vtg, Op, lp);
    k_attn_merge<<<dim3(1024), dim3(256), 0, stream>>>(Op, lp, obuf);

    k_gemm16<true><<<dim3(64, 16), dim3(256), 0, stream>>>(obuf, WpT, bp, hbuf);
    k_agg1t3<<<dim3(N_ / 4), dim3(256), 0, stream>>>(hbuf, ssrc, swv, offs, indeg, dinv, g1b, W3, t3);
    k_agg3<<<dim3(N_ / 4), dim3(256), 0, stream>>>(t3, ssrc, swv, offs, indeg, dinv, cvec, (float*)d_out);
}

// Round 10
// 213.951 us; speedup vs baseline: 1.1504x; 1.1504x over previous
//
#include <hip/hip_runtime.h>
#include <hip/hip_bf16.h>

typedef unsigned short ushort;
typedef __attribute__((ext_vector_type(8))) short short8;
typedef __attribute__((ext_vector_type(4))) float f32x4;

constexpr int N_  = 4096;
constexpr int TD_ = 768;
constexpr int ID_ = 512;
constexpr int H_  = 256;
constexpr int HD_ = 64;
constexpr int E_  = 131072;
constexpr int SPLITS = 8;  // R18: halves Op/lp traffic at same steady-state occupancy
constexpr float QSCALE = 0.125f * 1.44269504088896f;  // 1/sqrt(64) * log2(e)

#define MFMA16(a, b, c) __builtin_amdgcn_mfma_f32_16x16x32_bf16(a, b, c, 0, 0, 0)

__device__ inline ushort f2bf(float x) {
    union { float f; unsigned u; } v; v.f = x;
    unsigned r = v.u + 0x7fff + ((v.u >> 16) & 1);
    return (ushort)(r >> 16);
}
__device__ inline float lo2f(unsigned u) { union { unsigned x; float f; } v; v.x = u << 16; return v.f; }
__device__ inline float hi2f(unsigned u) { union { unsigned x; float f; } v; v.x = u & 0xffff0000u; return v.f; }

__device__ inline float exp2r(float x) {
    float r;
    asm("v_exp_f32 %0, %1" : "=v"(r) : "v"(x));
    return r;
}
__device__ inline unsigned pkbf(float lo, float hi) {
    union { float f; unsigned u; } a, b; a.f = lo; b.f = hi;
    return __builtin_amdgcn_perm(b.u + 0x8000u, a.u + 0x8000u, 0x07060302u);
}

__device__ inline void gl_lds16(const void* g, void* l) {
    __builtin_amdgcn_global_load_lds((const __attribute__((address_space(1))) unsigned int*)g,
                                     (__attribute__((address_space(3))) unsigned int*)l, 16, 0, 0);
}

// Stage 64x64 bf16 tile into LDS (wave-uniform base + lane*16B), XOR-swizzled 16B chunks.
__device__ inline void stage64(const ushort* g, long long strideEl, ushort* lds, int w, int l) {
    int r8 = l >> 3;
    int cc = (l & 7) ^ r8;
    #pragma unroll
    for (int p = 0; p < 2; p++) {
        int row = w * 16 + p * 8 + r8;
        gl_lds16(g + (long long)row * strideEl + cc * 8, lds + (w * 16 + p * 8) * 64);
    }
}
// Stage 16x64 bf16 tile (B for 64x16 GEMM tiles): waves 0,1 cover 8 rows each. [verified R8/R9]
__device__ inline void stageB16(const ushort* g, long long strideEl, ushort* lds, int w, int l) {
    if (w < 2) {
        int r8 = l >> 3;
        int row = w * 8 + r8;
        int cc = (l & 7) ^ (row & 7);
        gl_lds16(g + (long long)row * strideEl + cc * 8, lds + w * 512);
    }
}
// R22: stage 32x64 bf16 tile, all 4 waves cover 8 rows each (same XOR-chunk scheme; row&7 == r8).
__device__ inline void stageB32(const ushort* g, long long strideEl, ushort* lds, int w, int l) {
    int r8 = l >> 3;
    int row = w * 8 + r8;
    int cc = (l & 7) ^ r8;
    gl_lds16(g + (long long)row * strideEl + cc * 8, lds + w * 512);
}
__device__ inline int swz(int row, int kOff) {
    return row * 64 + ((((kOff >> 3) ^ (row & 7))) << 3);
}

// ---------------- prep: cvt (0..2591) | transposes (2592..2751) | edge count (2752..3263) ----------------

__global__ __launch_bounds__(256) void k_prep(const float* __restrict__ text, const float* __restrict__ img,
                                              const float* __restrict__ tw, const float* __restrict__ iw,
                                              const float* __restrict__ wq, const float* __restrict__ wk,
                                              const float* __restrict__ wv, const float* __restrict__ wo,
                                              const float* __restrict__ g1w, const float* __restrict__ g2w,
                                              const int* __restrict__ edst, int* __restrict__ indeg,
                                              ushort* __restrict__ textbf, ushort* __restrict__ imgbf,
                                              ushort* __restrict__ wobf,
                                              ushort* __restrict__ twT, ushort* __restrict__ iwT,
                                              ushort* __restrict__ wqT, ushort* __restrict__ wkT,
                                              ushort* __restrict__ wvT, ushort* __restrict__ g1wT,
                                              ushort* __restrict__ g2wT) {
    __shared__ float Ts[64][65];
    const int b = blockIdx.x;
    const int t = threadIdx.x;
    if (b >= 2752) {  // edge count
        int e = (b - 2752) * 256 + t;
        atomicAdd(&indeg[edst[e]], 1);
        return;
    }
    if (b < 2592) {  // linear bf16 cvt: text | img | wo
        size_t base = ((size_t)b * 256 + t) * 8;
        const size_t TXE = (size_t)N_ * TD_, IME = (size_t)N_ * ID_;
        const float* src; ushort* dst;
        if (base < TXE) { src = text + base; dst = textbf + base; }
        else if (base < TXE + IME) { src = img + (base - TXE); dst = imgbf + (base - TXE); }
        else { src = wo + (base - TXE - IME); dst = wobf + (base - TXE - IME); }
        float4 x = *(const float4*)src;
        float4 y = *(const float4*)(src + 4);
        ushort o[8] = { f2bf(x.x), f2bf(x.y), f2bf(x.z), f2bf(x.w),
                        f2bf(y.x), f2bf(y.y), f2bf(y.z), f2bf(y.w) };
        *(short8*)dst = *(const short8*)o;
        return;
    }
    int wb = b - 2592;
    const float* src; ushort* dst; int R, tile;
    if (wb < 48)       { src = tw;  dst = twT;  R = 768; tile = wb; }
    else if (wb < 80)  { src = iw;  dst = iwT;  R = 512; tile = wb - 48; }
    else if (wb < 96)  { src = wq;  dst = wqT;  R = 256; tile = wb - 80; }
    else if (wb < 112) { src = wk;  dst = wkT;  R = 256; tile = wb - 96; }
    else if (wb < 128) { src = wv;  dst = wvT;  R = 256; tile = wb - 112; }
    else if (wb < 144) { src = g1w; dst = g1wT; R = 256; tile = wb - 128; }
    else               { src = g2w; dst = g2wT; R = 256; tile = wb - 144; }
    const int r0 = (tile >> 2) * 64, c0 = (tile & 3) * 64;
    #pragma unroll
    for (int u = 0; u < 16; u++) {
        int lin = t + u * 256;
        int r = lin >> 6, c = lin & 63;
        Ts[r][c] = src[(size_t)(r0 + r) * 256 + c0 + c];
    }
    __syncthreads();
    #pragma unroll
    for (int u = 0; u < 16; u++) {
        int lin = t + u * 256;
        int c = lin >> 6, r = lin & 63;
        dst[(size_t)(c0 + c) * R + r0 + r] = f2bf(Ts[r][c]);
    }
}

// ---------------- combined projection 64x32 tiles (blocks 0..511, XCD-clustered) + degree scan (512) ----------------
// R22: 64x16 -> 64x32 tiles. A-panel staged 8x (was 16x): staging traffic 205 -> 123 MB,
// 16 block-MFMA per K-step on 12 KB staged (was 8 on 10 KB). Cost: grid 512 -> 2 blocks/CU
// (8 waves/CU) vs 4 before. Double-buffer prefetch unchanged.

__global__ __launch_bounds__(256, 4) void k_combined16(const ushort* __restrict__ text, const ushort* __restrict__ img,
                                                       const ushort* __restrict__ twT, const ushort* __restrict__ iwT,
                                                       const float* __restrict__ tb, const float* __restrict__ ib,
                                                       const int* __restrict__ indeg, int* __restrict__ offs,
                                                       float* __restrict__ dinv, ushort* __restrict__ out) {
    __shared__ ushort As[2][4096];
    __shared__ ushort Bs[2][2048];
    __shared__ ushort Cs[64 * 40];
    __shared__ int sums[256];
    const int b = blockIdx.x;
    const int t = threadIdx.x;
    if (b == 512) {  // exclusive scan of indeg + dinv [verified R8]
        int v[16]; int ssum = 0; int base = t * 16;
        #pragma unroll
        for (int k2 = 0; k2 < 16; k2++) { v[k2] = indeg[base + k2]; ssum += v[k2]; }
        sums[t] = ssum;
        __syncthreads();
        for (int off = 1; off < 256; off <<= 1) {
            int x = (t >= off) ? sums[t - off] : 0;
            __syncthreads();
            sums[t] += x;
            __syncthreads();
        }
        int excl = sums[t] - ssum;
        #pragma unroll
        for (int k2 = 0; k2 < 16; k2++) {
            offs[base + k2] = excl;
            excl += v[k2];
            dinv[base + k2] = 1.f / sqrtf((float)(v[k2] + 1));
        }
        return;
    }
    // XCD-clustered: the 8 bn-blocks sharing one A-panel land on one XCD (bijective over 512)
    const int xcd = b & 7, slot = b >> 3;
    const int bm = (xcd * 8 + (slot >> 3)) * 64, bn = (slot & 7) * 32;
    const int w = t >> 6, l = t & 63, q = l >> 4, i = l & 15;
    f32x4 acc1[2], acc2[2];
    #pragma unroll
    for (int nt = 0; nt < 2; nt++) { acc1[nt] = (f32x4){0, 0, 0, 0}; acc2[nt] = (f32x4){0, 0, 0, 0}; }
    auto stC = [&](int c, int buf) {
        if (c < 12) {
            stage64(text + (size_t)bm * TD_ + c * 64, TD_, As[buf], w, l);
            stageB32(twT + (size_t)bn * TD_ + c * 64, TD_, Bs[buf], w, l);
        } else {
            stage64(img + (size_t)bm * ID_ + (c - 12) * 64, ID_, As[buf], w, l);
            stageB32(iwT + (size_t)bn * ID_ + (c - 12) * 64, ID_, Bs[buf], w, l);
        }
    };
    stC(0, 0);
    for (int c = 0; c < 20; c++) {
        __syncthreads();
        if (c + 1 < 20) stC(c + 1, (c + 1) & 1);
        const ushort* Ab = As[c & 1];
        const ushort* Bb = Bs[c & 1];
        #pragma unroll
        for (int kb = 0; kb < 2; kb++) {
            short8 af = *(const short8*)&Ab[swz(w * 16 + i, kb * 32 + q * 8)];
            #pragma unroll
            for (int nt = 0; nt < 2; nt++) {
                short8 bfr = *(const short8*)&Bb[swz(nt * 16 + i, kb * 32 + q * 8)];
                if (c < 12) acc1[nt] = MFMA16(af, bfr, acc1[nt]);
                else        acc2[nt] = MFMA16(af, bfr, acc2[nt]);
            }
        }
    }
    __syncthreads();
    #pragma unroll
    for (int nt = 0; nt < 2; nt++) {
        float b1 = tb[bn + nt * 16 + i], b2 = ib[bn + nt * 16 + i];
        #pragma unroll
        for (int r = 0; r < 4; r++) {
            float v = fmaxf(acc1[nt][r] + b1, 0.f) + fmaxf(acc2[nt][r] + b2, 0.f);
            Cs[(w * 16 + q * 4 + r) * 40 + nt * 16 + i] = f2bf(v);
        }
    }
    __syncthreads();
    {
        int row = t >> 2, c8 = (t & 3) * 8;
        *(short8*)(out + (size_t)(bm + row) * H_ + bn + c8) = *(const short8*)&Cs[row * 40 + c8];
    }
}

// ---------------- QKV (0..767, XCD-clustered) + scatter (768..1279) + wo-fold (1280..1295)
//                  + bp (1296) + W3 = g2w@cls (1297..1300) + cvec (1301)  [R19] ----------------

__global__ __launch_bounds__(256) void k_qkv_scatfold(const ushort* __restrict__ A,
                                                      const ushort* __restrict__ WqT, const ushort* __restrict__ WkT,
                                                      const ushort* __restrict__ WvT,
                                                      const float* __restrict__ bq, const float* __restrict__ bk,
                                                      const float* __restrict__ bv,
                                                      ushort* __restrict__ Qg, ushort* __restrict__ Kg,
                                                      ushort* __restrict__ Vtg,
                                                      const int* __restrict__ esrc, const int* __restrict__ edst,
                                                      const int* __restrict__ offs, const float* __restrict__ dinv,
                                                      int* __restrict__ pos, int* __restrict__ ssrc,
                                                      float* __restrict__ swv,
                                                      const ushort* __restrict__ g1wT, const ushort* __restrict__ wobf,
                                                      const float* __restrict__ bo,
                                                      ushort* __restrict__ WpT, float* __restrict__ bp,
                                                      const float* __restrict__ g2wf, const float* __restrict__ cwf,
                                                      const float* __restrict__ g2bf, const float* __restrict__ cbf,
                                                      float* __restrict__ W3, float* __restrict__ cvec) {
    __shared__ ushort As[2][4096];
    __shared__ ushort Bs[2][4096];
    __shared__ ushort Cs[64 * 72];
    const int b = blockIdx.x;
    const int t = threadIdx.x;
    const int w = t >> 6, l = t & 63, q = l >> 4, i = l & 15;

    if (b >= 768) {
        if (b < 1280) {  // edge scatter
            int e = (b - 768) * 256 + t;
            int s = esrc[e], d = edst[e];
            int p = atomicAdd(&pos[d], 1);
            int idx = offs[d] + p;
            ssrc[idx] = s;
            swv[idx] = dinv[s] * dinv[d];
            return;
        }
        if (b >= 1297) {  // R19: W3[r][c] = sum_k g2w[r][k]*cls[k][c]; cvec[c] = cls^T g2b + cb
            if (b == 1301) {
                if (t < 3) {
                    float acc = 0.f;
                    for (int d = 0; d < 256; d++) acc += cwf[d * 3 + t] * g2bf[d];
                    cvec[t] = acc + cbf[t];
                }
                return;
            }
            int r = (b - 1297) * 64 + (t & 63), c = t >> 6;
            if (c < 3) {
                float acc = 0.f;
                const float* row = g2wf + (size_t)r * 256;
                for (int k = 0; k < 256; k++) acc += row[k] * cwf[k * 3 + c];
                W3[r * 3 + c] = acc;
            }
            return;
        }
        if (b == 1296) {  // bp[c] = sum_m bo[m] * g1wT[c][m]
            float acc = 0.f;
            const ushort* row = g1wT + (size_t)t * 256;
            for (int m8 = 0; m8 < 256; m8 += 8) {
                #pragma unroll
                for (int j = 0; j < 8; j++) acc += bo[m8 + j] * lo2f(((unsigned)row[m8 + j]) << 16);
            }
            bp[t] = acc;
            return;
        }
        // wo-fold tile: WpT[a][b2] = sum_m g1wT[a][m]*wobf[b2][m]
        const int f = b - 1280;
        const int bm = (f >> 2) * 64, bn = (f & 3) * 64;
        f32x4 acc[4];
        #pragma unroll
        for (int nt = 0; nt < 4; nt++) acc[nt] = (f32x4){0, 0, 0, 0};
        stage64(g1wT + (size_t)bm * H_, H_, As[0], w, l);
        stage64(wobf + (size_t)bn * H_, H_, Bs[0], w, l);
        for (int c = 0; c < 4; c++) {
            __syncthreads();
            if (c < 3) {
                stage64(g1wT + (size_t)bm * H_ + (c + 1) * 64, H_, As[(c + 1) & 1], w, l);
                stage64(wobf + (size_t)bn * H_ + (c + 1) * 64, H_, Bs[(c + 1) & 1], w, l);
            }
            const ushort* Ab = As[c & 1];
            const ushort* Bb = Bs[c & 1];
            #pragma unroll
            for (int kb = 0; kb < 2; kb++) {
                short8 af = *(const short8*)&Ab[swz(w * 16 + i, kb * 32 + q * 8)];
                #pragma unroll
                for (int nt = 0; nt < 4; nt++) {
                    short8 bfr = *(const short8*)&Bb[swz(nt * 16 + i, kb * 32 + q * 8)];
                    acc[nt] = MFMA16(af, bfr, acc[nt]);
                }
            }
        }
        __syncthreads();
        #pragma unroll
        for (int nt = 0; nt < 4; nt++)
            #pragma unroll
            for (int r = 0; r < 4; r++)
                Cs[(w * 16 + q * 4 + r) * 72 + nt * 16 + i] = f2bf(acc[nt][r]);
        __syncthreads();
        int rr = t >> 2, c16 = (t & 3) * 16;
        short8 v0 = *(const short8*)&Cs[rr * 72 + c16];
        short8 v1 = *(const short8*)&Cs[rr * 72 + c16 + 8];
        ushort* dstp = WpT + (size_t)(bm + rr) * H_ + bn + c16;
        *(short8*)dstp = v0;
        *(short8*)(dstp + 8) = v1;
        return;
    }

    // QKV: z = b>>8; within z, XCD-clustered remap [R18]
    const int z = b >> 8, r = b & 255;
    const int xcd = r & 7, slot = r >> 3;
    const int bm = (xcd * 8 + (slot >> 2)) * 64, head = slot & 3;
    const ushort* WT = (z == 0) ? WqT : (z == 1) ? WkT : WvT;
    const float* bias = (z == 0) ? bq : (z == 1) ? bk : bv;
    f32x4 acc[4];
    #pragma unroll
    for (int nt = 0; nt < 4; nt++) acc[nt] = (f32x4){0, 0, 0, 0};

    stage64(A + (size_t)bm * H_, H_, As[0], w, l);
    stage64(WT + (size_t)(head * 64) * H_, H_, Bs[0], w, l);
    for (int c = 0; c < 4; c++) {
        __syncthreads();
        if (c < 3) {
            stage64(A + (size_t)bm * H_ + (c + 1) * 64, H_, As[(c + 1) & 1], w, l);
            stage64(WT + (size_t)(head * 64) * H_ + (c + 1) * 64, H_, Bs[(c + 1) & 1], w, l);
        }
        const ushort* Ab = As[c & 1];
        const ushort* Bb = Bs[c & 1];
        #pragma unroll
        for (int kb = 0; kb < 2; kb++) {
            short8 af = *(const short8*)&Ab[swz(w * 16 + i, kb * 32 + q * 8)];
            #pragma unroll
            for (int nt = 0; nt < 4; nt++) {
                short8 bfr = *(const short8*)&Bb[swz(nt * 16 + i, kb * 32 + q * 8)];
                acc[nt] = MFMA16(af, bfr, acc[nt]);
            }
        }
    }
    __syncthreads();
    #pragma unroll
    for (int nt = 0; nt < 4; nt++) {
        float bv_ = bias[head * 64 + nt * 16 + i];
        #pragma unroll
        for (int r2 = 0; r2 < 4; r2++) {
            float v = acc[nt][r2] + bv_;
            if (z == 0) v *= QSCALE;
            if (z < 2) Cs[(w * 16 + q * 4 + r2) * 72 + nt * 16 + i] = f2bf(v);
            else       Cs[(nt * 16 + i) * 72 + w * 16 + q * 4 + r2] = f2bf(v);  // transposed [d][n]
        }
    }
    __syncthreads();
    int rr = t >> 2, c16 = (t & 3) * 16;
    short8 v0 = *(const short8*)&Cs[rr * 72 + c16];
    short8 v1 = *(const short8*)&Cs[rr * 72 + c16 + 8];
    ushort* dst;
    if (z < 2) dst = ((z == 0) ? Qg : Kg) + (size_t)head * N_ * HD_ + (size_t)(bm + rr) * HD_ + c16;
    else       dst = Vtg + (size_t)head * HD_ * N_ + (size_t)rr * N_ + bm + c16;
    *(short8*)dst = v0;
    *(short8*)(dst + 8) = v1;
}

// ---------------- flash attention: S^T math, single-buf K/V LDS staging, split-8, 128 queries/block ----------------
// R22: reverted to the R20 staged form. R21's direct-global variant was latency-bound (MfmaUtil
// 9.5%, HBM 6%): kf/vf addresses stride 128B per lane -> 16-line gather per wave load. LDS
// staging converts that into coalesced 16B/lane loads once; keep it.

__global__ __launch_bounds__(256) void k_attn_mfma(const ushort* __restrict__ Qg, const ushort* __restrict__ Kg,
                                                   const ushort* __restrict__ Vtg, ushort* __restrict__ Op,
                                                   float* __restrict__ lp) {
    __shared__ ushort Ks[4096];
    __shared__ ushort Vs[4096];
    __shared__ ushort Ps[4][2][16 * 72];
    const int head = blockIdx.y, r0 = blockIdx.x * 128, z = blockIdx.z;
    const int t = threadIdx.x, w = t >> 6, l = t & 63, q = l >> 4, i = l & 15;
    const int rw = (i ^ (i >> 1)) & 7;
    ushort* Pw0 = &Ps[w][0][0];
    ushort* Pw1 = &Ps[w][1][0];

    short8 qf[2][2];  // [qt][kb]
    #pragma unroll
    for (int qt = 0; qt < 2; qt++)
        #pragma unroll
        for (int kb = 0; kb < 2; kb++)
            qf[qt][kb] = *(const short8*)(Qg + ((size_t)head * N_ + r0 + qt * 64 + w * 16 + i) * HD_ + kb * 32 + q * 8);

    f32x4 Oacc[2][4];
    float lacc[2] = {0.f, 0.f};
    #pragma unroll
    for (int qt = 0; qt < 2; qt++)
        #pragma unroll
        for (int dt = 0; dt < 4; dt++) Oacc[qt][dt] = (f32x4){0, 0, 0, 0};

    const int NT = 64 / SPLITS;
    const int cb0 = z * NT;
    for (int it = 0; it < NT; it++) {
        const int cb = cb0 + it;
        __syncthreads();
        stage64(Kg + ((size_t)head * N_ + (size_t)cb * 64) * HD_, HD_, Ks, w, l);
        stage64(Vtg + (size_t)head * HD_ * N_ + cb * 64, N_, Vs, w, l);
        __syncthreads();

        // S^T for both query tiles; kf loaded once, used twice
        f32x4 St[2][4];
        #pragma unroll
        for (int qt = 0; qt < 2; qt++)
            #pragma unroll
            for (int kt = 0; kt < 4; kt++) St[qt][kt] = (f32x4){0, 0, 0, 0};
        #pragma unroll
        for (int kb = 0; kb < 2; kb++) {
            #pragma unroll
            for (int kt = 0; kt < 4; kt++) {
                short8 kf = *(const short8*)&Ks[swz(kt * 16 + i, kb * 32 + q * 8)];
                St[0][kt] = MFMA16(kf, qf[0][kb], St[0][kt]);
                St[1][kt] = MFMA16(kf, qf[1][kb], St[1][kt]);
            }
        }
        // exp/pack BOTH query tiles into their own Ps halves (wave-private, no barrier needed)
        #pragma unroll
        for (int kt = 0; kt < 4; kt++) {
            float a0 = exp2r(St[0][kt][0]), a1 = exp2r(St[0][kt][1]);
            float a2 = exp2r(St[0][kt][2]), a3 = exp2r(St[0][kt][3]);
            lacc[0] += (a0 + a1) + (a2 + a3);
            float b0 = exp2r(St[1][kt][0]), b1 = exp2r(St[1][kt][1]);
            float b2 = exp2r(St[1][kt][2]), b3 = exp2r(St[1][kt][3]);
            lacc[1] += (b0 + b1) + (b2 + b3);
            int off = i * 72 + (((2 * kt + (q >> 1)) ^ rw) << 3) + ((q & 1) << 2);
            uint2 va; va.x = pkbf(a0, a1); va.y = pkbf(a2, a3);
            *(uint2*)&Pw0[off] = va;
            uint2 vb; vb.x = pkbf(b0, b1); vb.y = pkbf(b2, b3);
            *(uint2*)&Pw1[off] = vb;
        }
        // fused PV: vf read once, used for both query tiles
        #pragma unroll
        for (int kb = 0; kb < 2; kb++) {
            int poff = i * 72 + (((4 * kb + q) ^ rw) << 3);
            short8 pf0 = *(const short8*)&Pw0[poff];
            short8 pf1 = *(const short8*)&Pw1[poff];
            #pragma unroll
            for (int dt = 0; dt < 4; dt++) {
                short8 vf = *(const short8*)&Vs[swz(dt * 16 + i, kb * 32 + q * 8)];
                Oacc[0][dt] = MFMA16(vf, pf0, Oacc[0][dt]);
                Oacc[1][dt] = MFMA16(vf, pf1, Oacc[1][dt]);
            }
        }
    }

    #pragma unroll
    for (int qt = 0; qt < 2; qt++) {
        lacc[qt] += __shfl_xor(lacc[qt], 16);
        lacc[qt] += __shfl_xor(lacc[qt], 32);
    }

    const size_t sh = ((size_t)z * 4 + head) * N_;
    #pragma unroll
    for (int qt = 0; qt < 2; qt++) {
        const int row = r0 + qt * 64 + w * 16 + i;
        #pragma unroll
        for (int dt = 0; dt < 4; dt++) {
            uint2 v;
            v.x = pkbf(Oacc[qt][dt][0], Oacc[qt][dt][1]);
            v.y = pkbf(Oacc[qt][dt][2], Oacc[qt][dt][3]);
            *(uint2*)&Op[(sh + row) * HD_ + dt * 16 + q * 4] = v;
        }
        if (l < 16) lp[sh + r0 + qt * 64 + w * 16 + l] = lacc[qt];
    }
}

// merge SPLITS splits -> obuf bf16 [N][H]
__global__ __launch_bounds__(256) void k_attn_merge(const ushort* __restrict__ Op, const float* __restrict__ lp,
                                                    ushort* __restrict__ obuf) {
    const int t = threadIdx.x;
    const int idx = blockIdx.x * 16 + (t >> 4);
    const int h = idx >> 12, n = idx & 4095;
    const int d4 = (t & 15) * 4;
    float lsum = 0.f;
    float acc[4] = {0.f, 0.f, 0.f, 0.f};
    #pragma unroll
    for (int s = 0; s < SPLITS; s++) {
        size_t sh = ((size_t)s * 4 + h) * N_ + n;
        lsum += lp[sh];
        uint2 o4 = *(const uint2*)&Op[sh * HD_ + d4];
        acc[0] += lo2f(o4.x); acc[1] += hi2f(o4.x);
        acc[2] += lo2f(o4.y); acc[3] += hi2f(o4.y);
    }
    float inv = 1.f / lsum;
    uint2 res;
    res.x = pkbf(acc[0] * inv, acc[1] * inv);
    res.y = pkbf(acc[2] * inv, acc[3] * inv);
    *(uint2*)&obuf[(size_t)n * H_ + h * HD_ + d4] = res;
}

// ---------------- bf16 MFMA GEMM, 64x16 tiles (grid 64x16) [verified R9] ----------------

template <bool BIAS>
__global__ __launch_bounds__(256, 4) void k_gemm16(const ushort* __restrict__ A, const ushort* __restrict__ BT,
                                                   const float* __restrict__ bias, ushort* __restrict__ outb) {
    __shared__ ushort As[2][4096];
    __shared__ ushort Bs[2][1024];
    __shared__ ushort Cs[64 * 24];
    const int bm = blockIdx.x * 64, bn = blockIdx.y * 16;
    const int t = threadIdx.x, w = t >> 6, l = t & 63, q = l >> 4, i = l & 15;
    f32x4 acc = {0, 0, 0, 0};
    stage64(A + (size_t)bm * H_, H_, As[0], w, l);
    stageB16(BT + (size_t)bn * H_, H_, Bs[0], w, l);
    for (int c = 0; c < 4; c++) {
        __syncthreads();
        if (c < 3) {
            stage64(A + (size_t)bm * H_ + (c + 1) * 64, H_, As[(c + 1) & 1], w, l);
            stageB16(BT + (size_t)bn * H_ + (c + 1) * 64, H_, Bs[(c + 1) & 1], w, l);
        }
        const ushort* Ab = As[c & 1];
        const ushort* Bb = Bs[c & 1];
        #pragma unroll
        for (int kb = 0; kb < 2; kb++) {
            short8 af = *(const short8*)&Ab[swz(w * 16 + i, kb * 32 + q * 8)];
            short8 bfr = *(const short8*)&Bb[swz(i, kb * 32 + q * 8)];
            acc = MFMA16(af, bfr, acc);
        }
    }
    __syncthreads();
    float bb = BIAS ? bias[bn + i] : 0.f;
    #pragma unroll
    for (int r = 0; r < 4; r++)
        Cs[(w * 16 + q * 4 + r) * 24 + i] = f2bf(acc[r] + bb);
    __syncthreads();
    if (t < 128) {
        int row = t >> 1, h8 = (t & 1) * 8;
        *(short8*)(outb + (size_t)(bm + row) * H_ + bn + h8) = *(const short8*)&Cs[row * 24 + h8];
    }
}

// ---------------- R20: GCN layer-1 aggregation FUSED with t3 = relu(agg+bias) @ W3 ----------------

__global__ __launch_bounds__(256) void k_agg1t3(const ushort* __restrict__ h, const int* __restrict__ ssrc,
                                                const float* __restrict__ sw, const int* __restrict__ offs,
                                                const int* __restrict__ indeg, const float* __restrict__ dinv,
                                                const float* __restrict__ bias, const float* __restrict__ W3,
                                                float* __restrict__ t3) {
    const int t = threadIdx.x;
    const int j = __builtin_amdgcn_readfirstlane(blockIdx.x * 4 + (t >> 6));
    const int l = t & 63;
    const int d0 = l * 4;
    float dj = dinv[j];
    uint2 hv = *(const uint2*)&h[(size_t)j * H_ + d0];
    float s2 = dj * dj;
    float a0 = s2 * lo2f(hv.x), a1 = s2 * hi2f(hv.x), a2 = s2 * lo2f(hv.y), a3 = s2 * hi2f(hv.y);
    int start = offs[j], cnt = indeg[j];
    for (int e = 0; e < cnt; e++) {
        int s = ssrc[start + e];
        float wg = sw[start + e];
        uint2 v = *(const uint2*)&h[(size_t)s * H_ + d0];
        a0 += wg * lo2f(v.x); a1 += wg * hi2f(v.x);
        a2 += wg * lo2f(v.y); a3 += wg * hi2f(v.y);
    }
    a0 = fmaxf(a0 + bias[d0], 0.f);
    a1 = fmaxf(a1 + bias[d0 + 1], 0.f);
    a2 = fmaxf(a2 + bias[d0 + 2], 0.f);
    a3 = fmaxf(a3 + bias[d0 + 3], 0.f);
    // t3 contribution of channels d0..d0+3 (W3 rows d0..d0+3, 12 consecutive f32)
    const float* wr = W3 + d0 * 3;
    float4 wa = *(const float4*)(wr);
    float4 wb = *(const float4*)(wr + 4);
    float4 wc = *(const float4*)(wr + 8);
    float p0 = a0 * wa.x + a1 * wa.w + a2 * wb.z + a3 * wc.y;
    float p1 = a0 * wa.y + a1 * wb.x + a2 * wb.w + a3 * wc.z;
    float p2 = a0 * wa.z + a1 * wb.y + a2 * wc.x + a3 * wc.w;
    #pragma unroll
    for (int off = 32; off > 0; off >>= 1) {
        p0 += __shfl_xor(p0, off);
        p1 += __shfl_xor(p1, off);
        p2 += __shfl_xor(p2, off);
    }
    if (l == 0) {
        t3[j * 3 + 0] = p0;
        t3[j * 3 + 1] = p1;
        t3[j * 3 + 2] = p2;
    }
}

// ---------------- R19: 3-dim aggregation + const -> out. Lanes over edges (handles deg>64). ----------------

__global__ __launch_bounds__(256) void k_agg3(const float* __restrict__ t3, const int* __restrict__ ssrc,
                                              const float* __restrict__ sw, const int* __restrict__ offs,
                                              const int* __restrict__ indeg, const float* __restrict__ dinv,
                                              const float* __restrict__ cvec, float* __restrict__ out) {
    const int t = threadIdx.x;
    const int j = __builtin_amdgcn_readfirstlane(blockIdx.x * 4 + (t >> 6));
    const int l = t & 63;
    int start = offs[j], cnt = indeg[j];
    float p0 = 0.f, p1 = 0.f, p2 = 0.f;
    for (int e = l; e < cnt; e += 64) {
        int s = ssrc[start + e];
        float wg = sw[start + e];
        p0 += wg * t3[s * 3 + 0];
        p1 += wg * t3[s * 3 + 1];
        p2 += wg * t3[s * 3 + 2];
    }
    #pragma unroll
    for (int off = 32; off > 0; off >>= 1) {
        p0 += __shfl_xor(p0, off);
        p1 += __shfl_xor(p1, off);
        p2 += __shfl_xor(p2, off);
    }
    if (l == 0) {
        float dj = dinv[j];
        float s2 = dj * dj;
        out[j * 3 + 0] = p0 + s2 * t3[j * 3 + 0] + cvec[0];
        out[j * 3 + 1] = p1 + s2 * t3[j * 3 + 1] + cvec[1];
        out[j * 3 + 2] = p2 + s2 * t3[j * 3 + 2] + cvec[2];
    }
}

// ---------------- launch ----------------

extern "C" void kernel_launch(void* const* d_in, const int* in_sizes, int n_in,
                              void* d_out, int out_size, void* d_ws, size_t ws_size,
                              hipStream_t stream) {
    const float* text = (const float*)d_in[0];
    const float* img  = (const float*)d_in[1];
    const int*   eidx = (const int*)d_in[2];
    const float* tw  = (const float*)d_in[3];
    const float* tb  = (const float*)d_in[4];
    const float* iw  = (const float*)d_in[5];
    const float* ib  = (const float*)d_in[6];
    const float* wq  = (const float*)d_in[7];
    const float* bq  = (const float*)d_in[8];
    const float* wk  = (const float*)d_in[9];
    const float* bk  = (const float*)d_in[10];
    const float* wv  = (const float*)d_in[11];
    const float* bv  = (const float*)d_in[12];
    const float* wo  = (const float*)d_in[13];
    const float* bo  = (const float*)d_in[14];
    const float* g1w = (const float*)d_in[15];
    const float* g1b = (const float*)d_in[16];
    const float* g2w = (const float*)d_in[17];
    const float* g2b = (const float*)d_in[18];
    const float* cw  = (const float*)d_in[19];
    const float* cbv = (const float*)d_in[20];

    char* W = (char*)d_ws;
    size_t cur = 0;
    auto alloc = [&](size_t sz) { char* p = W + cur; cur += (sz + 255) & ~(size_t)255; return p; };

    // persistent region
    float* dinv  = (float*)alloc(N_ * 4);
    float* swv   = (float*)alloc(E_ * 4);
    int* indeg   = (int*)alloc(N_ * 4);   // indeg, offs, pos contiguous (each 16 KB, 256-aligned)
    int* offs    = (int*)alloc(N_ * 4);
    int* pos     = (int*)alloc(N_ * 4);
    int* ssrc    = (int*)alloc(E_ * 4);
    ushort* Qg   = (ushort*)alloc((size_t)N_ * H_ * 2);
    ushort* Kg   = (ushort*)alloc((size_t)N_ * H_ * 2);
    ushort* Vtg  = (ushort*)alloc((size_t)N_ * H_ * 2);
    ushort* obuf = (ushort*)alloc((size_t)N_ * H_ * 2);
    ushort* WpT  = (ushort*)alloc((size_t)H_ * H_ * 2);
    float* bp    = (float*)alloc(H_ * 4);
    ushort* g1wT = (ushort*)alloc((size_t)H_ * H_ * 2);
    ushort* g2wT = (ushort*)alloc((size_t)H_ * H_ * 2);
    ushort* wobf = (ushort*)alloc((size_t)H_ * H_ * 2);
    float* lp    = (float*)alloc((size_t)SPLITS * 4 * N_ * 4);
    float* t3    = (float*)alloc((size_t)N_ * 3 * 4);
    float* W3    = (float*)alloc(256 * 3 * 4);
    float* cvec  = (float*)alloc(16);
    char* S = W + cur;  // phase-overlaid scratch

    // phase 1: conversions + projections (~13 MB)
    ushort* textbf = (ushort*)S;
    ushort* imgbf  = textbf + (size_t)N_ * TD_;
    ushort* twT    = imgbf + (size_t)N_ * ID_;
    ushort* iwT    = twT + (size_t)TD_ * H_;
    ushort* wqT    = iwT + (size_t)ID_ * H_;
    ushort* wkT    = wqT + (size_t)H_ * H_;
    ushort* wvT    = wkT + (size_t)H_ * H_;
    ushort* combbf = wvT + (size_t)H_ * H_;
    // phase 2: Op = SPLITS*4*N*64 bf16 = 16 MB (overlays phase 1)
    ushort* Op = (ushort*)S;
    // phase 3: post-attention (Op dead after merge)
    ushort* hbuf  = (ushort*)S;

    const int* esrc = eidx;
    const int* edst = eidx + E_;

    // R20: k_init dispatch replaced by one memset node (indeg+offs+pos are contiguous)
    hipMemsetAsync(indeg, 0, (size_t)3 * N_ * 4, stream);
    k_prep<<<dim3(3264), dim3(256), 0, stream>>>(text, img, tw, iw, wq, wk, wv, wo, g1w, g2w,
                                                 edst, indeg,
                                                 textbf, imgbf, wobf, twT, iwT, wqT, wkT, wvT, g1wT, g2wT);
    k_combined16<<<dim3(513), dim3(256), 0, stream>>>(textbf, imgbf, twT, iwT, tb, ib,
                                                      indeg, offs, dinv, combbf);
    k_qkv_scatfold<<<dim3(1302), dim3(256), 0, stream>>>(combbf, wqT, wkT, wvT, bq, bk, bv, Qg, Kg, Vtg,
                                                         esrc, edst, offs, dinv, pos, ssrc, swv,
                                                         g1wT, wobf, bo, WpT, bp,
                                                         g2w, cw, g2b, cbv, W3, cvec);
    k_attn_mfma<<<dim3(32, 4, SPLITS), dim3(256), 0, stream>>>(Qg, Kg, Vtg, Op, lp);
    k_attn_merge<<<dim3(1024), dim3(256), 0, stream>>>(Op, lp, obuf);

    k_gemm16<true><<<dim3(64, 16), dim3(256), 0, stream>>>(obuf, WpT, bp, hbuf);
    k_agg1t3<<<dim3(N_ / 4), dim3(256), 0, stream>>>(hbuf, ssrc, swv, offs, indeg, dinv, g1b, W3, t3);
    k_agg3<<<dim3(N_ / 4), dim3(256), 0, stream>>>(t3, ssrc, swv, offs, indeg, dinv, cvec, (float*)d_out);
}

// Round 11
// 208.226 us; speedup vs baseline: 1.1820x; 1.0275x over previous
//
#include <hip/hip_runtime.h>
#include <hip/hip_bf16.h>

typedef unsigned short ushort;
typedef __attribute__((ext_vector_type(8))) short short8;
typedef __attribute__((ext_vector_type(4))) float f32x4;

constexpr int N_  = 4096;
constexpr int TD_ = 768;
constexpr int ID_ = 512;
constexpr int H_  = 256;
constexpr int HD_ = 64;
constexpr int E_  = 131072;
constexpr int SPLITS = 8;  // R18: halves Op/lp traffic at same steady-state occupancy
constexpr float QSCALE = 0.125f * 1.44269504088896f;  // 1/sqrt(64) * log2(e)

#define MFMA16(a, b, c) __builtin_amdgcn_mfma_f32_16x16x32_bf16(a, b, c, 0, 0, 0)

__device__ inline ushort f2bf(float x) {
    union { float f; unsigned u; } v; v.f = x;
    unsigned r = v.u + 0x7fff + ((v.u >> 16) & 1);
    return (ushort)(r >> 16);
}
__device__ inline float lo2f(unsigned u) { union { unsigned x; float f; } v; v.x = u << 16; return v.f; }
__device__ inline float hi2f(unsigned u) { union { unsigned x; float f; } v; v.x = u & 0xffff0000u; return v.f; }

__device__ inline float exp2r(float x) {
    float r;
    asm("v_exp_f32 %0, %1" : "=v"(r) : "v"(x));
    return r;
}
__device__ inline unsigned pkbf(float lo, float hi) {
    union { float f; unsigned u; } a, b; a.f = lo; b.f = hi;
    return __builtin_amdgcn_perm(b.u + 0x8000u, a.u + 0x8000u, 0x07060302u);
}

__device__ inline void gl_lds16(const void* g, void* l) {
    __builtin_amdgcn_global_load_lds((const __attribute__((address_space(1))) unsigned int*)g,
                                     (__attribute__((address_space(3))) unsigned int*)l, 16, 0, 0);
}

// Stage 64x64 bf16 tile into LDS (wave-uniform base + lane*16B), XOR-swizzled 16B chunks.
__device__ inline void stage64(const ushort* g, long long strideEl, ushort* lds, int w, int l) {
    int r8 = l >> 3;
    int cc = (l & 7) ^ r8;
    #pragma unroll
    for (int p = 0; p < 2; p++) {
        int row = w * 16 + p * 8 + r8;
        gl_lds16(g + (long long)row * strideEl + cc * 8, lds + (w * 16 + p * 8) * 64);
    }
}
// Stage 16x64 bf16 tile (B for 64x16 GEMM tiles): waves 0,1 cover 8 rows each. [verified R8/R9]
__device__ inline void stageB16(const ushort* g, long long strideEl, ushort* lds, int w, int l) {
    if (w < 2) {
        int r8 = l >> 3;
        int row = w * 8 + r8;
        int cc = (l & 7) ^ (row & 7);
        gl_lds16(g + (long long)row * strideEl + cc * 8, lds + w * 512);
    }
}
__device__ inline int swz(int row, int kOff) {
    return row * 64 + ((((kOff >> 3) ^ (row & 7))) << 3);
}

// ---------------- prep: cvt (0..2591) | transposes (2592..2751) | edge count (2752..3263) ----------------

__global__ __launch_bounds__(256) void k_prep(const float* __restrict__ text, const float* __restrict__ img,
                                              const float* __restrict__ tw, const float* __restrict__ iw,
                                              const float* __restrict__ wq, const float* __restrict__ wk,
                                              const float* __restrict__ wv, const float* __restrict__ wo,
                                              const float* __restrict__ g1w, const float* __restrict__ g2w,
                                              const int* __restrict__ edst, int* __restrict__ indeg,
                                              ushort* __restrict__ textbf, ushort* __restrict__ imgbf,
                                              ushort* __restrict__ wobf,
                                              ushort* __restrict__ twT, ushort* __restrict__ iwT,
                                              ushort* __restrict__ wqT, ushort* __restrict__ wkT,
                                              ushort* __restrict__ wvT, ushort* __restrict__ g1wT,
                                              ushort* __restrict__ g2wT) {
    __shared__ float Ts[64][65];
    const int b = blockIdx.x;
    const int t = threadIdx.x;
    if (b >= 2752) {  // edge count
        int e = (b - 2752) * 256 + t;
        atomicAdd(&indeg[edst[e]], 1);
        return;
    }
    if (b < 2592) {  // linear bf16 cvt: text | img | wo
        size_t base = ((size_t)b * 256 + t) * 8;
        const size_t TXE = (size_t)N_ * TD_, IME = (size_t)N_ * ID_;
        const float* src; ushort* dst;
        if (base < TXE) { src = text + base; dst = textbf + base; }
        else if (base < TXE + IME) { src = img + (base - TXE); dst = imgbf + (base - TXE); }
        else { src = wo + (base - TXE - IME); dst = wobf + (base - TXE - IME); }
        float4 x = *(const float4*)src;
        float4 y = *(const float4*)(src + 4);
        ushort o[8] = { f2bf(x.x), f2bf(x.y), f2bf(x.z), f2bf(x.w),
                        f2bf(y.x), f2bf(y.y), f2bf(y.z), f2bf(y.w) };
        *(short8*)dst = *(const short8*)o;
        return;
    }
    int wb = b - 2592;
    const float* src; ushort* dst; int R, tile;
    if (wb < 48)       { src = tw;  dst = twT;  R = 768; tile = wb; }
    else if (wb < 80)  { src = iw;  dst = iwT;  R = 512; tile = wb - 48; }
    else if (wb < 96)  { src = wq;  dst = wqT;  R = 256; tile = wb - 80; }
    else if (wb < 112) { src = wk;  dst = wkT;  R = 256; tile = wb - 96; }
    else if (wb < 128) { src = wv;  dst = wvT;  R = 256; tile = wb - 112; }
    else if (wb < 144) { src = g1w; dst = g1wT; R = 256; tile = wb - 128; }
    else               { src = g2w; dst = g2wT; R = 256; tile = wb - 144; }
    const int r0 = (tile >> 2) * 64, c0 = (tile & 3) * 64;
    #pragma unroll
    for (int u = 0; u < 16; u++) {
        int lin = t + u * 256;
        int r = lin >> 6, c = lin & 63;
        Ts[r][c] = src[(size_t)(r0 + r) * 256 + c0 + c];
    }
    __syncthreads();
    #pragma unroll
    for (int u = 0; u < 16; u++) {
        int lin = t + u * 256;
        int c = lin >> 6, r = lin & 63;
        dst[(size_t)(c0 + c) * R + r0 + r] = f2bf(Ts[r][c]);
    }
}

// ---------------- combined projection 64x16 tiles (blocks 0..1023, XCD-clustered) + degree scan ----------------
// R23: reverted to 64x16 / grid 1025 (R22's 64x32 grid-513 = 2 blocks/CU lost more TLP than the
// halved A-staging gained: +4.3 us). 4 blocks/CU is load-bearing for every GEMM in this chain.

__global__ __launch_bounds__(256, 4) void k_combined16(const ushort* __restrict__ text, const ushort* __restrict__ img,
                                                       const ushort* __restrict__ twT, const ushort* __restrict__ iwT,
                                                       const float* __restrict__ tb, const float* __restrict__ ib,
                                                       const int* __restrict__ indeg, int* __restrict__ offs,
                                                       float* __restrict__ dinv, ushort* __restrict__ out) {
    __shared__ ushort As[2][4096];
    __shared__ ushort Bs[2][1024];
    __shared__ ushort Cs[64 * 24];
    __shared__ int sums[256];
    const int b = blockIdx.x;
    const int t = threadIdx.x;
    if (b == 1024) {  // exclusive scan of indeg + dinv [verified R8]
        int v[16]; int ssum = 0; int base = t * 16;
        #pragma unroll
        for (int k2 = 0; k2 < 16; k2++) { v[k2] = indeg[base + k2]; ssum += v[k2]; }
        sums[t] = ssum;
        __syncthreads();
        for (int off = 1; off < 256; off <<= 1) {
            int x = (t >= off) ? sums[t - off] : 0;
            __syncthreads();
            sums[t] += x;
            __syncthreads();
        }
        int excl = sums[t] - ssum;
        #pragma unroll
        for (int k2 = 0; k2 < 16; k2++) {
            offs[base + k2] = excl;
            excl += v[k2];
            dinv[base + k2] = 1.f / sqrtf((float)(v[k2] + 1));
        }
        return;
    }
    const int xcd = b & 7, slot = b >> 3;
    const int bm = (xcd * 8 + (slot >> 4)) * 64, bn = (slot & 15) * 16;
    const int w = t >> 6, l = t & 63, q = l >> 4, i = l & 15;
    f32x4 acc1 = {0, 0, 0, 0}, acc2 = {0, 0, 0, 0};
    auto stC = [&](int c, int buf) {
        if (c < 12) {
            stage64(text + (size_t)bm * TD_ + c * 64, TD_, As[buf], w, l);
            stageB16(twT + (size_t)bn * TD_ + c * 64, TD_, Bs[buf], w, l);
        } else {
            stage64(img + (size_t)bm * ID_ + (c - 12) * 64, ID_, As[buf], w, l);
            stageB16(iwT + (size_t)bn * ID_ + (c - 12) * 64, ID_, Bs[buf], w, l);
        }
    };
    stC(0, 0);
    for (int c = 0; c < 20; c++) {
        __syncthreads();
        if (c + 1 < 20) stC(c + 1, (c + 1) & 1);
        const ushort* Ab = As[c & 1];
        const ushort* Bb = Bs[c & 1];
        #pragma unroll
        for (int kb = 0; kb < 2; kb++) {
            short8 af = *(const short8*)&Ab[swz(w * 16 + i, kb * 32 + q * 8)];
            short8 bfr = *(const short8*)&Bb[swz(i, kb * 32 + q * 8)];
            if (c < 12) acc1 = MFMA16(af, bfr, acc1);
            else        acc2 = MFMA16(af, bfr, acc2);
        }
    }
    __syncthreads();
    float b1 = tb[bn + i], b2 = ib[bn + i];
    #pragma unroll
    for (int r = 0; r < 4; r++) {
        float v = fmaxf(acc1[r] + b1, 0.f) + fmaxf(acc2[r] + b2, 0.f);
        Cs[(w * 16 + q * 4 + r) * 24 + i] = f2bf(v);
    }
    __syncthreads();
    if (t < 128) {
        int row = t >> 1, h8 = (t & 1) * 8;
        *(short8*)(out + (size_t)(bm + row) * H_ + bn + h8) = *(const short8*)&Cs[row * 24 + h8];
    }
}

// ---------------- QKV (0..767, XCD-clustered) + scatter (768..1279) + wo-fold (1280..1295)
//                  + bp (1296) + W3 = g2w@cls (1297..1300) + cvec (1301)  [R19] ----------------

__global__ __launch_bounds__(256) void k_qkv_scatfold(const ushort* __restrict__ A,
                                                      const ushort* __restrict__ WqT, const ushort* __restrict__ WkT,
                                                      const ushort* __restrict__ WvT,
                                                      const float* __restrict__ bq, const float* __restrict__ bk,
                                                      const float* __restrict__ bv,
                                                      ushort* __restrict__ Qg, ushort* __restrict__ Kg,
                                                      ushort* __restrict__ Vtg,
                                                      const int* __restrict__ esrc, const int* __restrict__ edst,
                                                      const int* __restrict__ offs, const float* __restrict__ dinv,
                                                      int* __restrict__ pos, int* __restrict__ ssrc,
                                                      float* __restrict__ swv,
                                                      const ushort* __restrict__ g1wT, const ushort* __restrict__ wobf,
                                                      const float* __restrict__ bo,
                                                      ushort* __restrict__ WpT, float* __restrict__ bp,
                                                      const float* __restrict__ g2wf, const float* __restrict__ cwf,
                                                      const float* __restrict__ g2bf, const float* __restrict__ cbf,
                                                      float* __restrict__ W3, float* __restrict__ cvec) {
    __shared__ ushort As[2][4096];
    __shared__ ushort Bs[2][4096];
    __shared__ ushort Cs[64 * 72];
    const int b = blockIdx.x;
    const int t = threadIdx.x;
    const int w = t >> 6, l = t & 63, q = l >> 4, i = l & 15;

    if (b >= 768) {
        if (b < 1280) {  // edge scatter
            int e = (b - 768) * 256 + t;
            int s = esrc[e], d = edst[e];
            int p = atomicAdd(&pos[d], 1);
            int idx = offs[d] + p;
            ssrc[idx] = s;
            swv[idx] = dinv[s] * dinv[d];
            return;
        }
        if (b >= 1297) {  // R19: W3[r][c] = sum_k g2w[r][k]*cls[k][c]; cvec[c] = cls^T g2b + cb
            if (b == 1301) {
                if (t < 3) {
                    float acc = 0.f;
                    for (int d = 0; d < 256; d++) acc += cwf[d * 3 + t] * g2bf[d];
                    cvec[t] = acc + cbf[t];
                }
                return;
            }
            int r = (b - 1297) * 64 + (t & 63), c = t >> 6;
            if (c < 3) {
                float acc = 0.f;
                const float* row = g2wf + (size_t)r * 256;
                for (int k = 0; k < 256; k++) acc += row[k] * cwf[k * 3 + c];
                W3[r * 3 + c] = acc;
            }
            return;
        }
        if (b == 1296) {  // bp[c] = sum_m bo[m] * g1wT[c][m]
            float acc = 0.f;
            const ushort* row = g1wT + (size_t)t * 256;
            for (int m8 = 0; m8 < 256; m8 += 8) {
                #pragma unroll
                for (int j = 0; j < 8; j++) acc += bo[m8 + j] * lo2f(((unsigned)row[m8 + j]) << 16);
            }
            bp[t] = acc;
            return;
        }
        // wo-fold tile: WpT[a][b2] = sum_m g1wT[a][m]*wobf[b2][m]
        const int f = b - 1280;
        const int bm = (f >> 2) * 64, bn = (f & 3) * 64;
        f32x4 acc[4];
        #pragma unroll
        for (int nt = 0; nt < 4; nt++) acc[nt] = (f32x4){0, 0, 0, 0};
        stage64(g1wT + (size_t)bm * H_, H_, As[0], w, l);
        stage64(wobf + (size_t)bn * H_, H_, Bs[0], w, l);
        for (int c = 0; c < 4; c++) {
            __syncthreads();
            if (c < 3) {
                stage64(g1wT + (size_t)bm * H_ + (c + 1) * 64, H_, As[(c + 1) & 1], w, l);
                stage64(wobf + (size_t)bn * H_ + (c + 1) * 64, H_, Bs[(c + 1) & 1], w, l);
            }
            const ushort* Ab = As[c & 1];
            const ushort* Bb = Bs[c & 1];
            #pragma unroll
            for (int kb = 0; kb < 2; kb++) {
                short8 af = *(const short8*)&Ab[swz(w * 16 + i, kb * 32 + q * 8)];
                #pragma unroll
                for (int nt = 0; nt < 4; nt++) {
                    short8 bfr = *(const short8*)&Bb[swz(nt * 16 + i, kb * 32 + q * 8)];
                    acc[nt] = MFMA16(af, bfr, acc[nt]);
                }
            }
        }
        __syncthreads();
        #pragma unroll
        for (int nt = 0; nt < 4; nt++)
            #pragma unroll
            for (int r = 0; r < 4; r++)
                Cs[(w * 16 + q * 4 + r) * 72 + nt * 16 + i] = f2bf(acc[nt][r]);
        __syncthreads();
        int rr = t >> 2, c16 = (t & 3) * 16;
        short8 v0 = *(const short8*)&Cs[rr * 72 + c16];
        short8 v1 = *(const short8*)&Cs[rr * 72 + c16 + 8];
        ushort* dstp = WpT + (size_t)(bm + rr) * H_ + bn + c16;
        *(short8*)dstp = v0;
        *(short8*)(dstp + 8) = v1;
        return;
    }

    // QKV: z = b>>8; within z, XCD-clustered remap [R18]
    const int z = b >> 8, r = b & 255;
    const int xcd = r & 7, slot = r >> 3;
    const int bm = (xcd * 8 + (slot >> 2)) * 64, head = slot & 3;
    const ushort* WT = (z == 0) ? WqT : (z == 1) ? WkT : WvT;
    const float* bias = (z == 0) ? bq : (z == 1) ? bk : bv;
    f32x4 acc[4];
    #pragma unroll
    for (int nt = 0; nt < 4; nt++) acc[nt] = (f32x4){0, 0, 0, 0};

    stage64(A + (size_t)bm * H_, H_, As[0], w, l);
    stage64(WT + (size_t)(head * 64) * H_, H_, Bs[0], w, l);
    for (int c = 0; c < 4; c++) {
        __syncthreads();
        if (c < 3) {
            stage64(A + (size_t)bm * H_ + (c + 1) * 64, H_, As[(c + 1) & 1], w, l);
            stage64(WT + (size_t)(head * 64) * H_ + (c + 1) * 64, H_, Bs[(c + 1) & 1], w, l);
        }
        const ushort* Ab = As[c & 1];
        const ushort* Bb = Bs[c & 1];
        #pragma unroll
        for (int kb = 0; kb < 2; kb++) {
            short8 af = *(const short8*)&Ab[swz(w * 16 + i, kb * 32 + q * 8)];
            #pragma unroll
            for (int nt = 0; nt < 4; nt++) {
                short8 bfr = *(const short8*)&Bb[swz(nt * 16 + i, kb * 32 + q * 8)];
                acc[nt] = MFMA16(af, bfr, acc[nt]);
            }
        }
    }
    __syncthreads();
    #pragma unroll
    for (int nt = 0; nt < 4; nt++) {
        float bv_ = bias[head * 64 + nt * 16 + i];
        #pragma unroll
        for (int r2 = 0; r2 < 4; r2++) {
            float v = acc[nt][r2] + bv_;
            if (z == 0) v *= QSCALE;
            if (z < 2) Cs[(w * 16 + q * 4 + r2) * 72 + nt * 16 + i] = f2bf(v);
            else       Cs[(nt * 16 + i) * 72 + w * 16 + q * 4 + r2] = f2bf(v);  // transposed [d][n]
        }
    }
    __syncthreads();
    int rr = t >> 2, c16 = (t & 3) * 16;
    short8 v0 = *(const short8*)&Cs[rr * 72 + c16];
    short8 v1 = *(const short8*)&Cs[rr * 72 + c16 + 8];
    ushort* dst;
    if (z < 2) dst = ((z == 0) ? Qg : Kg) + (size_t)head * N_ * HD_ + (size_t)(bm + rr) * HD_ + c16;
    else       dst = Vtg + (size_t)head * HD_ * N_ + (size_t)rr * N_ + bm + c16;
    *(short8*)dst = v0;
    *(short8*)(dst + 8) = v1;
}

// ---------------- flash attention: S^T math, single-buf K/V LDS staging, split-8, 128 queries/block ----------------
// R16: fused-PV (vf read once, feeds both Oacc[qt]); 20 b128 LDS reads/wave-tile. R18: SPLITS=8.
// R22 confirmed staging is load-bearing (direct-global variant: MfmaUtil 9.5%, 16-line gather/load).

__global__ __launch_bounds__(256) void k_attn_mfma(const ushort* __restrict__ Qg, const ushort* __restrict__ Kg,
                                                   const ushort* __restrict__ Vtg, ushort* __restrict__ Op,
                                                   float* __restrict__ lp) {
    __shared__ ushort Ks[4096];
    __shared__ ushort Vs[4096];
    __shared__ ushort Ps[4][2][16 * 72];
    const int head = blockIdx.y, r0 = blockIdx.x * 128, z = blockIdx.z;
    const int t = threadIdx.x, w = t >> 6, l = t & 63, q = l >> 4, i = l & 15;
    const int rw = (i ^ (i >> 1)) & 7;
    ushort* Pw0 = &Ps[w][0][0];
    ushort* Pw1 = &Ps[w][1][0];

    short8 qf[2][2];  // [qt][kb]
    #pragma unroll
    for (int qt = 0; qt < 2; qt++)
        #pragma unroll
        for (int kb = 0; kb < 2; kb++)
            qf[qt][kb] = *(const short8*)(Qg + ((size_t)head * N_ + r0 + qt * 64 + w * 16 + i) * HD_ + kb * 32 + q * 8);

    f32x4 Oacc[2][4];
    float lacc[2] = {0.f, 0.f};
    #pragma unroll
    for (int qt = 0; qt < 2; qt++)
        #pragma unroll
        for (int dt = 0; dt < 4; dt++) Oacc[qt][dt] = (f32x4){0, 0, 0, 0};

    const int NT = 64 / SPLITS;
    const int cb0 = z * NT;
    for (int it = 0; it < NT; it++) {
        const int cb = cb0 + it;
        __syncthreads();
        stage64(Kg + ((size_t)head * N_ + (size_t)cb * 64) * HD_, HD_, Ks, w, l);
        stage64(Vtg + (size_t)head * HD_ * N_ + cb * 64, N_, Vs, w, l);
        __syncthreads();

        // S^T for both query tiles; kf loaded once, used twice
        f32x4 St[2][4];
        #pragma unroll
        for (int qt = 0; qt < 2; qt++)
            #pragma unroll
            for (int kt = 0; kt < 4; kt++) St[qt][kt] = (f32x4){0, 0, 0, 0};
        #pragma unroll
        for (int kb = 0; kb < 2; kb++) {
            #pragma unroll
            for (int kt = 0; kt < 4; kt++) {
                short8 kf = *(const short8*)&Ks[swz(kt * 16 + i, kb * 32 + q * 8)];
                St[0][kt] = MFMA16(kf, qf[0][kb], St[0][kt]);
                St[1][kt] = MFMA16(kf, qf[1][kb], St[1][kt]);
            }
        }
        // exp/pack BOTH query tiles into their own Ps halves (wave-private, no barrier needed)
        #pragma unroll
        for (int kt = 0; kt < 4; kt++) {
            float a0 = exp2r(St[0][kt][0]), a1 = exp2r(St[0][kt][1]);
            float a2 = exp2r(St[0][kt][2]), a3 = exp2r(St[0][kt][3]);
            lacc[0] += (a0 + a1) + (a2 + a3);
            float b0 = exp2r(St[1][kt][0]), b1 = exp2r(St[1][kt][1]);
            float b2 = exp2r(St[1][kt][2]), b3 = exp2r(St[1][kt][3]);
            lacc[1] += (b0 + b1) + (b2 + b3);
            int off = i * 72 + (((2 * kt + (q >> 1)) ^ rw) << 3) + ((q & 1) << 2);
            uint2 va; va.x = pkbf(a0, a1); va.y = pkbf(a2, a3);
            *(uint2*)&Pw0[off] = va;
            uint2 vb; vb.x = pkbf(b0, b1); vb.y = pkbf(b2, b3);
            *(uint2*)&Pw1[off] = vb;
        }
        // fused PV: vf read once, used for both query tiles
        #pragma unroll
        for (int kb = 0; kb < 2; kb++) {
            int poff = i * 72 + (((4 * kb + q) ^ rw) << 3);
            short8 pf0 = *(const short8*)&Pw0[poff];
            short8 pf1 = *(const short8*)&Pw1[poff];
            #pragma unroll
            for (int dt = 0; dt < 4; dt++) {
                short8 vf = *(const short8*)&Vs[swz(dt * 16 + i, kb * 32 + q * 8)];
                Oacc[0][dt] = MFMA16(vf, pf0, Oacc[0][dt]);
                Oacc[1][dt] = MFMA16(vf, pf1, Oacc[1][dt]);
            }
        }
    }

    #pragma unroll
    for (int qt = 0; qt < 2; qt++) {
        lacc[qt] += __shfl_xor(lacc[qt], 16);
        lacc[qt] += __shfl_xor(lacc[qt], 32);
    }

    const size_t sh = ((size_t)z * 4 + head) * N_;
    #pragma unroll
    for (int qt = 0; qt < 2; qt++) {
        const int row = r0 + qt * 64 + w * 16 + i;
        #pragma unroll
        for (int dt = 0; dt < 4; dt++) {
            uint2 v;
            v.x = pkbf(Oacc[qt][dt][0], Oacc[qt][dt][1]);
            v.y = pkbf(Oacc[qt][dt][2], Oacc[qt][dt][3]);
            *(uint2*)&Op[(sh + row) * HD_ + dt * 16 + q * 4] = v;
        }
        if (l < 16) lp[sh + r0 + qt * 64 + w * 16 + l] = lacc[qt];
    }
}

// merge SPLITS splits -> obuf bf16 [N][H]
__global__ __launch_bounds__(256) void k_attn_merge(const ushort* __restrict__ Op, const float* __restrict__ lp,
                                                    ushort* __restrict__ obuf) {
    const int t = threadIdx.x;
    const int idx = blockIdx.x * 16 + (t >> 4);
    const int h = idx >> 12, n = idx & 4095;
    const int d4 = (t & 15) * 4;
    float lsum = 0.f;
    float acc[4] = {0.f, 0.f, 0.f, 0.f};
    #pragma unroll
    for (int s = 0; s < SPLITS; s++) {
        size_t sh = ((size_t)s * 4 + h) * N_ + n;
        lsum += lp[sh];
        uint2 o4 = *(const uint2*)&Op[sh * HD_ + d4];
        acc[0] += lo2f(o4.x); acc[1] += hi2f(o4.x);
        acc[2] += lo2f(o4.y); acc[3] += hi2f(o4.y);
    }
    float inv = 1.f / lsum;
    uint2 res;
    res.x = pkbf(acc[0] * inv, acc[1] * inv);
    res.y = pkbf(acc[2] * inv, acc[3] * inv);
    *(uint2*)&obuf[(size_t)n * H_ + h * HD_ + d4] = res;
}

// ---------------- bf16 MFMA GEMM, 64x16 tiles (grid 64x16) [verified R9] ----------------

template <bool BIAS>
__global__ __launch_bounds__(256, 4) void k_gemm16(const ushort* __restrict__ A, const ushort* __restrict__ BT,
                                                   const float* __restrict__ bias, ushort* __restrict__ outb) {
    __shared__ ushort As[2][4096];
    __shared__ ushort Bs[2][1024];
    __shared__ ushort Cs[64 * 24];
    const int bm = blockIdx.x * 64, bn = blockIdx.y * 16;
    const int t = threadIdx.x, w = t >> 6, l = t & 63, q = l >> 4, i = l & 15;
    f32x4 acc = {0, 0, 0, 0};
    stage64(A + (size_t)bm * H_, H_, As[0], w, l);
    stageB16(BT + (size_t)bn * H_, H_, Bs[0], w, l);
    for (int c = 0; c < 4; c++) {
        __syncthreads();
        if (c < 3) {
            stage64(A + (size_t)bm * H_ + (c + 1) * 64, H_, As[(c + 1) & 1], w, l);
            stageB16(BT + (size_t)bn * H_ + (c + 1) * 64, H_, Bs[(c + 1) & 1], w, l);
        }
        const ushort* Ab = As[c & 1];
        const ushort* Bb = Bs[c & 1];
        #pragma unroll
        for (int kb = 0; kb < 2; kb++) {
            short8 af = *(const short8*)&Ab[swz(w * 16 + i, kb * 32 + q * 8)];
            short8 bfr = *(const short8*)&Bb[swz(i, kb * 32 + q * 8)];
            acc = MFMA16(af, bfr, acc);
        }
    }
    __syncthreads();
    float bb = BIAS ? bias[bn + i] : 0.f;
    #pragma unroll
    for (int r = 0; r < 4; r++)
        Cs[(w * 16 + q * 4 + r) * 24 + i] = f2bf(acc[r] + bb);
    __syncthreads();
    if (t < 128) {
        int row = t >> 1, h8 = (t & 1) * 8;
        *(short8*)(outb + (size_t)(bm + row) * H_ + bn + h8) = *(const short8*)&Cs[row * 24 + h8];
    }
}

// ---------------- R20: GCN layer-1 aggregation FUSED with t3 = relu(agg+bias) @ W3 ----------------

__global__ __launch_bounds__(256) void k_agg1t3(const ushort* __restrict__ h, const int* __restrict__ ssrc,
                                                const float* __restrict__ sw, const int* __restrict__ offs,
                                                const int* __restrict__ indeg, const float* __restrict__ dinv,
                                                const float* __restrict__ bias, const float* __restrict__ W3,
                                                float* __restrict__ t3) {
    const int t = threadIdx.x;
    const int j = __builtin_amdgcn_readfirstlane(blockIdx.x * 4 + (t >> 6));
    const int l = t & 63;
    const int d0 = l * 4;
    float dj = dinv[j];
    uint2 hv = *(const uint2*)&h[(size_t)j * H_ + d0];
    float s2 = dj * dj;
    float a0 = s2 * lo2f(hv.x), a1 = s2 * hi2f(hv.x), a2 = s2 * lo2f(hv.y), a3 = s2 * hi2f(hv.y);
    int start = offs[j], cnt = indeg[j];
    for (int e = 0; e < cnt; e++) {
        int s = ssrc[start + e];
        float wg = sw[start + e];
        uint2 v = *(const uint2*)&h[(size_t)s * H_ + d0];
        a0 += wg * lo2f(v.x); a1 += wg * hi2f(v.x);
        a2 += wg * lo2f(v.y); a3 += wg * hi2f(v.y);
    }
    a0 = fmaxf(a0 + bias[d0], 0.f);
    a1 = fmaxf(a1 + bias[d0 + 1], 0.f);
    a2 = fmaxf(a2 + bias[d0 + 2], 0.f);
    a3 = fmaxf(a3 + bias[d0 + 3], 0.f);
    // t3 contribution of channels d0..d0+3 (W3 rows d0..d0+3, 12 consecutive f32)
    const float* wr = W3 + d0 * 3;
    float4 wa = *(const float4*)(wr);
    float4 wb = *(const float4*)(wr + 4);
    float4 wc = *(const float4*)(wr + 8);
    float p0 = a0 * wa.x + a1 * wa.w + a2 * wb.z + a3 * wc.y;
    float p1 = a0 * wa.y + a1 * wb.x + a2 * wb.w + a3 * wc.z;
    float p2 = a0 * wa.z + a1 * wb.y + a2 * wc.x + a3 * wc.w;
    #pragma unroll
    for (int off = 32; off > 0; off >>= 1) {
        p0 += __shfl_xor(p0, off);
        p1 += __shfl_xor(p1, off);
        p2 += __shfl_xor(p2, off);
    }
    if (l == 0) {
        t3[j * 3 + 0] = p0;
        t3[j * 3 + 1] = p1;
        t3[j * 3 + 2] = p2;
    }
}

// ---------------- R19: 3-dim aggregation + const -> out. Lanes over edges (handles deg>64). ----------------

__global__ __launch_bounds__(256) void k_agg3(const float* __restrict__ t3, const int* __restrict__ ssrc,
                                              const float* __restrict__ sw, const int* __restrict__ offs,
                                              const int* __restrict__ indeg, const float* __restrict__ dinv,
                                              const float* __restrict__ cvec, float* __restrict__ out) {
    const int t = threadIdx.x;
    const int j = __builtin_amdgcn_readfirstlane(blockIdx.x * 4 + (t >> 6));
    const int l = t & 63;
    int start = offs[j], cnt = indeg[j];
    float p0 = 0.f, p1 = 0.f, p2 = 0.f;
    for (int e = l; e < cnt; e += 64) {
        int s = ssrc[start + e];
        float wg = sw[start + e];
        p0 += wg * t3[s * 3 + 0];
        p1 += wg * t3[s * 3 + 1];
        p2 += wg * t3[s * 3 + 2];
    }
    #pragma unroll
    for (int off = 32; off > 0; off >>= 1) {
        p0 += __shfl_xor(p0, off);
        p1 += __shfl_xor(p1, off);
        p2 += __shfl_xor(p2, off);
    }
    if (l == 0) {
        float dj = dinv[j];
        float s2 = dj * dj;
        out[j * 3 + 0] = p0 + s2 * t3[j * 3 + 0] + cvec[0];
        out[j * 3 + 1] = p1 + s2 * t3[j * 3 + 1] + cvec[1];
        out[j * 3 + 2] = p2 + s2 * t3[j * 3 + 2] + cvec[2];
    }
}

// ---------------- launch ----------------

extern "C" void kernel_launch(void* const* d_in, const int* in_sizes, int n_in,
                              void* d_out, int out_size, void* d_ws, size_t ws_size,
                              hipStream_t stream) {
    const float* text = (const float*)d_in[0];
    const float* img  = (const float*)d_in[1];
    const int*   eidx = (const int*)d_in[2];
    const float* tw  = (const float*)d_in[3];
    const float* tb  = (const float*)d_in[4];
    const float* iw  = (const float*)d_in[5];
    const float* ib  = (const float*)d_in[6];
    const float* wq  = (const float*)d_in[7];
    const float* bq  = (const float*)d_in[8];
    const float* wk  = (const float*)d_in[9];
    const float* bk  = (const float*)d_in[10];
    const float* wv  = (const float*)d_in[11];
    const float* bv  = (const float*)d_in[12];
    const float* wo  = (const float*)d_in[13];
    const float* bo  = (const float*)d_in[14];
    const float* g1w = (const float*)d_in[15];
    const float* g1b = (const float*)d_in[16];
    const float* g2w = (const float*)d_in[17];
    const float* g2b = (const float*)d_in[18];
    const float* cw  = (const float*)d_in[19];
    const float* cbv = (const float*)d_in[20];

    char* W = (char*)d_ws;
    size_t cur = 0;
    auto alloc = [&](size_t sz) { char* p = W + cur; cur += (sz + 255) & ~(size_t)255; return p; };

    // persistent region
    float* dinv  = (float*)alloc(N_ * 4);
    float* swv   = (float*)alloc(E_ * 4);
    int* indeg   = (int*)alloc(N_ * 4);   // indeg, offs, pos contiguous (each 16 KB, 256-aligned)
    int* offs    = (int*)alloc(N_ * 4);
    int* pos     = (int*)alloc(N_ * 4);
    int* ssrc    = (int*)alloc(E_ * 4);
    ushort* Qg   = (ushort*)alloc((size_t)N_ * H_ * 2);
    ushort* Kg   = (ushort*)alloc((size_t)N_ * H_ * 2);
    ushort* Vtg  = (ushort*)alloc((size_t)N_ * H_ * 2);
    ushort* obuf = (ushort*)alloc((size_t)N_ * H_ * 2);
    ushort* WpT  = (ushort*)alloc((size_t)H_ * H_ * 2);
    float* bp    = (float*)alloc(H_ * 4);
    ushort* g1wT = (ushort*)alloc((size_t)H_ * H_ * 2);
    ushort* g2wT = (ushort*)alloc((size_t)H_ * H_ * 2);
    ushort* wobf = (ushort*)alloc((size_t)H_ * H_ * 2);
    float* lp    = (float*)alloc((size_t)SPLITS * 4 * N_ * 4);
    float* t3    = (float*)alloc((size_t)N_ * 3 * 4);
    float* W3    = (float*)alloc(256 * 3 * 4);
    float* cvec  = (float*)alloc(16);
    char* S = W + cur;  // phase-overlaid scratch

    // phase 1: conversions + projections (~13 MB)
    ushort* textbf = (ushort*)S;
    ushort* imgbf  = textbf + (size_t)N_ * TD_;
    ushort* twT    = imgbf + (size_t)N_ * ID_;
    ushort* iwT    = twT + (size_t)TD_ * H_;
    ushort* wqT    = iwT + (size_t)ID_ * H_;
    ushort* wkT    = wqT + (size_t)H_ * H_;
    ushort* wvT    = wkT + (size_t)H_ * H_;
    ushort* combbf = wvT + (size_t)H_ * H_;
    // phase 2: Op = SPLITS*4*N*64 bf16 = 16 MB (overlays phase 1)
    ushort* Op = (ushort*)S;
    // phase 3: post-attention (Op dead after merge)
    ushort* hbuf  = (ushort*)S;

    const int* esrc = eidx;
    const int* edst = eidx + E_;

    // R20: k_init dispatch replaced by one memset node (indeg+offs+pos are contiguous)
    hipMemsetAsync(indeg, 0, (size_t)3 * N_ * 4, stream);
    k_prep<<<dim3(3264), dim3(256), 0, stream>>>(text, img, tw, iw, wq, wk, wv, wo, g1w, g2w,
                                                 edst, indeg,
                                                 textbf, imgbf, wobf, twT, iwT, wqT, wkT, wvT, g1wT, g2wT);
    k_combined16<<<dim3(1025), dim3(256), 0, stream>>>(textbf, imgbf, twT, iwT, tb, ib,
                                                       indeg, offs, dinv, combbf);
    k_qkv_scatfold<<<dim3(1302), dim3(256), 0, stream>>>(combbf, wqT, wkT, wvT, bq, bk, bv, Qg, Kg, Vtg,
                                                         esrc, edst, offs, dinv, pos, ssrc, swv,
                                                         g1wT, wobf, bo, WpT, bp,
                                                         g2w, cw, g2b, cbv, W3, cvec);
    k_attn_mfma<<<dim3(32, 4, SPLITS), dim3(256), 0, stream>>>(Qg, Kg, Vtg, Op, lp);
    k_attn_merge<<<dim3(1024), dim3(256), 0, stream>>>(Op, lp, obuf);

    k_gemm16<true><<<dim3(64, 16), dim3(256), 0, stream>>>(obuf, WpT, bp, hbuf);
    k_agg1t3<<<dim3(N_ / 4), dim3(256), 0, stream>>>(hbuf, ssrc, swv, offs, indeg, dinv, g1b, W3, t3);
    k_agg3<<<dim3(N_ / 4), dim3(256), 0, stream>>>(t3, ssrc, swv, offs, indeg, dinv, cvec, (float*)d_out);
}